// Round 17
// baseline (2086.505 us; speedup 1.0000x reference)
//
#include <hip/hip_runtime.h>
#include <hip/hip_bf16.h>
#include <math.h>

#define LNUM 12
#define HNUM 12
#define EDIM 768
#define VDIM 50257
#define BDIM 2
#define TDIM 1024
#define BT (BDIM*TDIM)
#define E3 (3*EDIM)
#define E4 (4*EDIM)
#define NPB (2*((VDIM+127)/128))   // 786 per-64-col partials per row

typedef __bf16 bf16x8 __attribute__((ext_vector_type(8)));
typedef __bf16 bf16x4 __attribute__((ext_vector_type(4)));
typedef float f32x4 __attribute__((ext_vector_type(4)));

__device__ __forceinline__ float gelu_f(float x) {
    float u = 0.7978845608028654f * (x + 0.044715f * x * x * x);
    return 0.5f * x * (1.0f + tanhf(u));
}

// async global->LDS, 16B per lane
__device__ __forceinline__ void gl16(const void* g, void* l) {
    __builtin_amdgcn_global_load_lds(
        (const __attribute__((address_space(1))) unsigned int*)g,
        (__attribute__((address_space(3))) unsigned int*)l,
        16, 0, 0);
}

// ---------------------------------------------------------------- embedding
__global__ __launch_bounds__(256) void embed_kernel(
    const int* __restrict__ idx, const float* __restrict__ wte,
    const float* __restrict__ wpe, float* __restrict__ x)
{
    const int row = blockIdx.x;
    const int t = row % TDIM;
    const int tok = idx[row];
    const float* we = wte + (size_t)tok * EDIM;
    const float* pe = wpe + (size_t)t * EDIM;
    float* xr = x + (size_t)row * EDIM;
    for (int e = threadIdx.x; e < EDIM; e += 256) xr[e] = we[e] + pe[e];
}

// ---------------------------------------------------------------- layernorm (bf16 out)
__global__ __launch_bounds__(256) void ln_kernel(
    const float* __restrict__ in, const float* __restrict__ w,
    const float* __restrict__ b, __bf16* __restrict__ out)
{
    const int row = blockIdx.x * 4 + (threadIdx.x >> 6);
    const int lane = threadIdx.x & 63;
    const float4* xr = (const float4*)(in + (size_t)row * EDIM);
    float4 a0 = xr[lane], a1 = xr[64 + lane], a2 = xr[128 + lane];
    float s = a0.x + a0.y + a0.z + a0.w + a1.x + a1.y + a1.z + a1.w
            + a2.x + a2.y + a2.z + a2.w;
    #pragma unroll
    for (int off = 32; off; off >>= 1) s += __shfl_xor(s, off);
    const float mean = s * (1.0f / EDIM);
    float4 d0 = make_float4(a0.x - mean, a0.y - mean, a0.z - mean, a0.w - mean);
    float4 d1 = make_float4(a1.x - mean, a1.y - mean, a1.z - mean, a1.w - mean);
    float4 d2 = make_float4(a2.x - mean, a2.y - mean, a2.z - mean, a2.w - mean);
    float v = d0.x*d0.x + d0.y*d0.y + d0.z*d0.z + d0.w*d0.w
            + d1.x*d1.x + d1.y*d1.y + d1.z*d1.z + d1.w*d1.w
            + d2.x*d2.x + d2.y*d2.y + d2.z*d2.z + d2.w*d2.w;
    #pragma unroll
    for (int off = 32; off; off >>= 1) v += __shfl_xor(v, off);
    const float inv = rsqrtf(v * (1.0f / EDIM) + 1e-5f);
    const float4* w4 = (const float4*)w;
    const float4* b4 = (const float4*)b;
    __bf16* orow = out + (size_t)row * EDIM;
    #pragma unroll
    for (int c = 0; c < 3; ++c) {
        float4 dd = c == 0 ? d0 : (c == 1 ? d1 : d2);
        float4 ww = w4[c * 64 + lane], bb = b4[c * 64 + lane];
        bf16x4 o;
        o[0] = (__bf16)(dd.x * inv * ww.x + bb.x);
        o[1] = (__bf16)(dd.y * inv * ww.y + bb.y);
        o[2] = (__bf16)(dd.z * inv * ww.z + bb.z);
        o[3] = (__bf16)(dd.w * inv * ww.w + bb.w);
        *(bf16x4*)(orow + c * 256 + lane * 4) = o;
    }
}

// ------------------------------------------- split-K reduce + bias + residual + LN
__global__ __launch_bounds__(256) void redln_kernel(
    const float* __restrict__ ps, const float* __restrict__ bias,
    float* __restrict__ x, const float* __restrict__ w,
    const float* __restrict__ b, __bf16* __restrict__ out)
{
    const int row = blockIdx.x * 4 + (threadIdx.x >> 6);
    const int lane = threadIdx.x & 63;
    const float4* p0 = (const float4*)(ps + (size_t)row * EDIM);
    const float4* p1 = (const float4*)(ps + (size_t)(BT + row) * EDIM);
    float4* xr = (float4*)(x + (size_t)row * EDIM);
    const float4* b4 = (const float4*)bias;
    float4 a[3];
    #pragma unroll
    for (int c = 0; c < 3; ++c) {
        const int i = c * 64 + lane;
        float4 u = p0[i], v = p1[i], xx = xr[i], bb = b4[i];
        a[c] = make_float4(u.x + v.x + xx.x + bb.x, u.y + v.y + xx.y + bb.y,
                           u.z + v.z + xx.z + bb.z, u.w + v.w + xx.w + bb.w);
        xr[i] = a[c];
    }
    float s = a[0].x + a[0].y + a[0].z + a[0].w + a[1].x + a[1].y + a[1].z + a[1].w
            + a[2].x + a[2].y + a[2].z + a[2].w;
    #pragma unroll
    for (int off = 32; off; off >>= 1) s += __shfl_xor(s, off);
    const float mean = s * (1.0f / EDIM);
    float v = 0.f;
    #pragma unroll
    for (int c = 0; c < 3; ++c) {
        a[c] = make_float4(a[c].x - mean, a[c].y - mean, a[c].z - mean, a[c].w - mean);
        v += a[c].x * a[c].x + a[c].y * a[c].y + a[c].z * a[c].z + a[c].w * a[c].w;
    }
    #pragma unroll
    for (int off = 32; off; off >>= 1) v += __shfl_xor(v, off);
    const float inv = rsqrtf(v * (1.0f / EDIM) + 1e-5f);
    const float4* w4 = (const float4*)w;
    const float4* lb4 = (const float4*)b;
    __bf16* orow = out + (size_t)row * EDIM;
    #pragma unroll
    for (int c = 0; c < 3; ++c) {
        float4 ww = w4[c * 64 + lane], bb = lb4[c * 64 + lane];
        bf16x4 o;
        o[0] = (__bf16)(a[c].x * inv * ww.x + bb.x);
        o[1] = (__bf16)(a[c].y * inv * ww.y + bb.y);
        o[2] = (__bf16)(a[c].z * inv * ww.z + bb.z);
        o[3] = (__bf16)(a[c].w * inv * ww.w + bb.w);
        *(bf16x4*)(orow + c * 256 + lane * 4) = o;
    }
}

// ------------------------------------------------- weight convert: f32 [K][N] -> bf16 [N][K]
__global__ __launch_bounds__(256) void convt_kernel(
    const float* __restrict__ in, __bf16* __restrict__ out, int K, int N)
{
    in  += (size_t)blockIdx.z * K * N;
    out += (size_t)blockIdx.z * K * N;
    __shared__ float t[32][33];
    const int n0 = blockIdx.x * 32, k0 = blockIdx.y * 32;
    const int r = threadIdx.x >> 3, c = (threadIdx.x & 7) * 4;
    float4 v = *(const float4*)(in + (size_t)(k0 + r) * N + n0 + c);
    t[r][c + 0] = v.x; t[r][c + 1] = v.y; t[r][c + 2] = v.z; t[r][c + 3] = v.w;
    __syncthreads();
    bf16x4 o;
    o[0] = (__bf16)t[c + 0][r];
    o[1] = (__bf16)t[c + 1][r];
    o[2] = (__bf16)t[c + 2][r];
    o[3] = (__bf16)t[c + 3][r];
    *(bf16x4*)(out + (size_t)(n0 + r) * K + k0 + c) = o;
}

// ------------------------------------------------- elementwise f32 -> bf16 (wte)
__global__ __launch_bounds__(256) void cvt_kernel(
    const float* __restrict__ in, __bf16* __restrict__ out, long n4)
{
    for (long i = blockIdx.x * 256L + threadIdx.x; i < n4; i += (long)gridDim.x * 256L) {
        float4 v = ((const float4*)in)[i];
        out[i * 4 + 0] = (__bf16)v.x;
        out[i * 4 + 1] = (__bf16)v.y;
        out[i * 4 + 2] = (__bf16)v.z;
        out[i * 4 + 3] = (__bf16)v.w;
    }
}

// ---------------------------------------------------------------- MFMA GEMM (layer GEMMs)
template<int BM, int BN, int BK, bool BIAS, bool GELU_, bool RES_, bool OUTBF, bool NGUARD>
__global__ __launch_bounds__(256, 2) void mgemm(
    const __bf16* __restrict__ A, const __bf16* __restrict__ Bt,
    const float* __restrict__ bias, const float* __restrict__ res,
    void* __restrict__ Cout, int M, int N, int K, int lda)
{
    constexpr int WM = BM / 2, WN = BN / 2;
    constexpr int FM = WM / 16, FN = WN / 16;
    constexpr int KS = BK / 32;
    constexpr int TBA = BM * BK * 2;
    constexpr int TBB = BN * BK * 2;
    constexpr int rA = TBA / 4096, rB = TBB / 4096;
    constexpr int RPI = 2048 / BK;
    constexpr int CPR = BK / 8;
    __shared__ __align__(16) __bf16 As[3 * BM * BK];
    __shared__ __align__(16) __bf16 Bs[3 * BN * BK];
    const int tid = threadIdx.x;
    const int lane = tid & 63;
    const int wave = tid >> 6;
    const int wr = wave >> 1, wc = wave & 1;

    const int bm = blockIdx.y, bn = blockIdx.x;
    const int m0 = bm * BM;
    const int n0 = bn * BN;
    const int kbase = blockIdx.z * K;
    const size_t zoff = (size_t)blockIdx.z * M * N;

    const int srow = tid / CPR;
    const int skey = (BK == 32) ? ((srow >> 1) & 3) : (srow & 7);
    const int c0 = (tid % CPR) ^ skey;

    const __bf16* gA = A + (size_t)(m0 + srow) * lda + kbase + c0 * 8;
    const __bf16* gB[rB];
    #pragma unroll
    for (int r = 0; r < rB; ++r) {
        int nr = n0 + srow + r * RPI;
        if (NGUARD) nr = nr < N ? nr : N - 1;
        gB[r] = Bt + (size_t)nr * lda + kbase + c0 * 8;
    }

    const int fr = lane & 15;
    const int g = lane >> 4;
    const int fkey = (BK == 32) ? ((fr >> 1) & 3) : (fr & 7);

    f32x4 acc[FM][FN];
    #pragma unroll
    for (int i = 0; i < FM; i++)
        #pragma unroll
        for (int j = 0; j < FN; j++) acc[i][j] = (f32x4){0.f, 0.f, 0.f, 0.f};

    const int nt = K / BK;

    auto stage = [&](int kk, int b) {
        #pragma unroll
        for (int r = 0; r < rA; ++r)
            gl16(gA + (size_t)r * RPI * lda + kk, (char*)As + b * TBA + r * 4096 + tid * 16);
        #pragma unroll
        for (int r = 0; r < rB; ++r)
            gl16(gB[r] + kk, (char*)Bs + b * TBB + r * 4096 + tid * 16);
    };

    stage(0, 0);
    if (nt > 1) stage(BK, 1);

    int b0 = 0, b1 = 1, b2 = 2;
    for (int t = 0; t < nt; ++t) {
        if (t + 1 < nt) {
            static_assert(rA + rB == 4 || rA + rB == 6, "vmcnt literal");
            if constexpr (rA + rB == 4) asm volatile("s_waitcnt vmcnt(4)" ::: "memory");
            else                        asm volatile("s_waitcnt vmcnt(6)" ::: "memory");
        } else {
            asm volatile("s_waitcnt vmcnt(0)" ::: "memory");
        }
        asm volatile("s_barrier" ::: "memory");
        if (t + 2 < nt) stage((t + 2) * BK, b2);

        const char* pa = (const char*)As + b0 * TBA;
        const char* pb = (const char*)Bs + b0 * TBB;
        bf16x8 af[FM][KS], bfr[FN][KS];
        #pragma unroll
        for (int i = 0; i < FM; i++)
            #pragma unroll
            for (int kc = 0; kc < KS; kc++)
                af[i][kc] = *(const bf16x8*)(pa + (wr * WM + i * 16 + fr) * (2 * BK)
                                                + (((kc * 4 + g) ^ fkey) << 4));
        #pragma unroll
        for (int j = 0; j < FN; j++)
            #pragma unroll
            for (int kc = 0; kc < KS; kc++)
                bfr[j][kc] = *(const bf16x8*)(pb + (wc * WN + j * 16 + fr) * (2 * BK)
                                                 + (((kc * 4 + g) ^ fkey) << 4));
        #pragma unroll
        for (int kc = 0; kc < KS; kc++)
            #pragma unroll
            for (int i = 0; i < FM; i++)
                #pragma unroll
                for (int j = 0; j < FN; j++)
                    acc[i][j] = __builtin_amdgcn_mfma_f32_16x16x32_bf16(af[i][kc], bfr[j][kc], acc[i][j], 0, 0, 0);
        const int tmp = b0; b0 = b1; b1 = b2; b2 = tmp;
    }

    const int crow = g * 4;
    #pragma unroll
    for (int i = 0; i < FM; i++) {
        #pragma unroll
        for (int r = 0; r < 4; r++) {
            const int m = m0 + wr * WM + i * 16 + crow + r;
            #pragma unroll
            for (int j = 0; j < FN; j++) {
                const int n = n0 + wc * WN + j * 16 + fr;
                if (!NGUARD || n < N) {
                    float v = acc[i][j][r];
                    if (BIAS) v += bias[n];
                    if (GELU_) v = gelu_f(v);
                    if (RES_) v += res[(size_t)m * N + n];
                    if (OUTBF) ((__bf16*)Cout)[zoff + (size_t)m * N + n] = (__bf16)v;
                    else       ((float*)Cout)[zoff + (size_t)m * N + n] = v;
                }
            }
        }
    }
}

// ---------------------------------------------------------------- logits GEMM (deep prefetch)
// 512 threads (8 waves, 4M x 2N), BM=256 BN=128, BK=32 with SIX LDS buffers
// (144 KB): prefetch distance 4 K-tiles (~1300 MFMA-cycles) > ~900-cycle HBM
// latency at 1 block/CU. 3 loads/tile; steady-state vmcnt(9); one barrier/tile.
__global__ __launch_bounds__(512, 1) void lgemm(
    const __bf16* __restrict__ A, const __bf16* __restrict__ Bt,
    float* __restrict__ Cout, float* __restrict__ part, int M, int N, int K)
{
    __shared__ __align__(16) __bf16 As[6 * 256 * 32];   // 96 KB
    __shared__ __align__(16) __bf16 Bs[6 * 128 * 32];   // 48 KB
    const int tid = threadIdx.x;
    const int lane = tid & 63;
    const int wave = tid >> 6;
    const int wm = wave >> 1, wn = wave & 1;

    const int wg = blockIdx.x;
    const int bm = (wg >> 3) & 7;                 // all 8 bm of a bn on one XCD
    const int bn = (wg & 7) + ((wg >> 6) << 3);
    if (bn * 128 >= N) return;
    const int m0 = bm * 256, n0 = bn * 128;

    const int srow = tid >> 2;                    // 0..127
    const int c0 = (tid & 3) ^ ((srow >> 1) & 3); // inverse-swizzled 16B chunk
    const __bf16* gA = A + (size_t)(m0 + srow) * K + c0 * 8;
    int nr = n0 + srow; nr = nr < N ? nr : N - 1;
    const __bf16* gB = Bt + (size_t)nr * K + c0 * 8;

    const int fr = lane & 15;
    const int g = lane >> 4;
    const int fkey = (fr >> 1) & 3;
    const int slot = ((g ^ fkey) << 4);

    auto stage = [&](int t) {
        const int kk = t << 5;
        const int b = t % 6;
        gl16(gA + kk,                   (char*)As + b * 16384 + tid * 16);
        gl16(gA + (size_t)128 * K + kk, (char*)As + b * 16384 + 8192 + tid * 16);
        gl16(gB + kk,                   (char*)Bs + b * 8192 + tid * 16);
    };

    f32x4 acc[4][4];
    #pragma unroll
    for (int i = 0; i < 4; i++)
        #pragma unroll
        for (int j = 0; j < 4; j++) acc[i][j] = (f32x4){0.f, 0.f, 0.f, 0.f};

    const int nt = K >> 5;   // 24
    stage(0); stage(1); stage(2); stage(3);

    for (int t = 0; t < nt; ++t) {
        if (t + 4 <= nt)      asm volatile("s_waitcnt vmcnt(9)" ::: "memory");
        else if (t + 3 <= nt) asm volatile("s_waitcnt vmcnt(6)" ::: "memory");
        else if (t + 2 <= nt) asm volatile("s_waitcnt vmcnt(3)" ::: "memory");
        else                  asm volatile("s_waitcnt vmcnt(0)" ::: "memory");
        asm volatile("s_barrier" ::: "memory");   // buffer (t+4)%6 == (t-2)%6 free
        if (t + 4 < nt) stage(t + 4);

        const char* pa = (const char*)As + (t % 6) * 16384;
        const char* pb = (const char*)Bs + (t % 6) * 8192;
        bf16x8 af[4], bfr[4];
        #pragma unroll
        for (int i = 0; i < 4; ++i)
            af[i] = *(const bf16x8*)(pa + (wm * 64 + i * 16 + fr) * 64 + slot);
        #pragma unroll
        for (int j = 0; j < 4; ++j)
            bfr[j] = *(const bf16x8*)(pb + (wn * 64 + j * 16 + fr) * 64 + slot);
        __builtin_amdgcn_s_setprio(1);
        #pragma unroll
        for (int i = 0; i < 4; ++i)
            #pragma unroll
            for (int j = 0; j < 4; ++j)
                acc[i][j] = __builtin_amdgcn_mfma_f32_16x16x32_bf16(af[i], bfr[j], acc[i][j], 0, 0, 0);
        __builtin_amdgcn_s_setprio(0);
    }

    // epilogue: plain f32 stores + per-64-col sum-exp partials
    const int crow = g * 4;
    const int cg = bn * 2 + wn;
    #pragma unroll
    for (int i = 0; i < 4; i++) {
        #pragma unroll
        for (int r = 0; r < 4; r++) {
            const int m = m0 + wm * 64 + i * 16 + crow + r;
            float se = 0.f;
            #pragma unroll
            for (int j = 0; j < 4; j++) {
                const int n = n0 + wn * 64 + j * 16 + fr;
                if (n < N) {
                    float v = acc[i][j][r];
                    Cout[(size_t)m * N + n] = v;
                    se += __expf(v);
                }
            }
            se += __shfl_xor(se, 1); se += __shfl_xor(se, 2);
            se += __shfl_xor(se, 4); se += __shfl_xor(se, 8);
            if (fr == 0 && (n0 + wn * 64) < N)
                part[(size_t)m * NPB + cg] = se;
        }
    }
}

// ---------------------------------------------------------------- flash attention (bf16 MFMA)
__global__ __launch_bounds__(128) void fattn_kernel(
    const __bf16* __restrict__ qkv, __bf16* __restrict__ y)
{
    const int bq = gridDim.x - 1 - blockIdx.x;
    const int h = blockIdx.y, b = blockIdx.z;
    const int tid = threadIdx.x, lane = tid & 63, w = tid >> 6;
    const int fr = lane & 15, g = lane >> 4;

    __shared__ __align__(16) __bf16 Ks[64 * 64];
    __shared__ __align__(16) __bf16 Vt[64 * 64];
    __shared__ __align__(16) __bf16 Ps[2][16 * 64];

    const __bf16* base = qkv + (size_t)b * TDIM * E3;
    const int q0w = bq * 32 + w * 16;
    const int NT = (bq >> 1) + 1;
    const int last = NT - 1;

    bf16x8 qf[2];
    {
        const __bf16* qp = base + (size_t)(q0w + fr) * E3 + h * 64 + g * 8;
        qf[0] = *(const bf16x8*)qp;
        qf[1] = *(const bf16x8*)(qp + 32);
        const __bf16 sc = (__bf16)0.125f;   // exact (power of two)
        #pragma unroll
        for (int e = 0; e < 8; ++e) { qf[0][e] *= sc; qf[1][e] *= sc; }
    }

    const int r0 = tid >> 3, ch = tid & 7;
    bf16x8 kr[4], vr[4];

    #pragma unroll
    for (int it = 0; it < 4; ++it) {
        const int row = it * 16 + r0;
        const __bf16* gp = base + (size_t)row * E3 + EDIM + h * 64 + ch * 8;
        kr[it] = *(const bf16x8*)gp;
        vr[it] = *(const bf16x8*)(gp + EDIM);
    }
    #pragma unroll
    for (int it = 0; it < 4; ++it) {
        const int row = it * 16 + r0;
        *(bf16x8*)(Ks + row * 64 + ((ch ^ (row & 7)) << 3)) = kr[it];
        #pragma unroll
        for (int j = 0; j < 8; ++j) {
            const int d = ch * 8 + j;
            const int key = ((d >> 3) ^ d) & 7;
            Vt[d * 64 + ((((row >> 3) ^ key) << 3) + (row & 7))] = vr[it][j];
        }
    }
    __syncthreads();

    float m[4] = {-1e30f, -1e30f, -1e30f, -1e30f};
    float l[4] = {0.f, 0.f, 0.f, 0.f};
    f32x4 acc[4];
    #pragma unroll
    for (int jd = 0; jd < 4; ++jd) acc[jd] = (f32x4){0.f, 0.f, 0.f, 0.f};

    for (int kt = 0; kt < NT; ++kt) {
        if (kt < last) {
            const int k1 = (kt + 1) * 64;
            #pragma unroll
            for (int it = 0; it < 4; ++it) {
                const int row = it * 16 + r0;
                const __bf16* gp = base + (size_t)(k1 + row) * E3 + EDIM + h * 64 + ch * 8;
                kr[it] = *(const bf16x8*)gp;
                vr[it] = *(const bf16x8*)(gp + EDIM);
            }
        }

        const int k0 = kt * 64;
        f32x4 s[4];
        __builtin_amdgcn_s_setprio(1);
        #pragma unroll
        for (int jf = 0; jf < 4; ++jf) {
            const int krow = jf * 16 + fr;
            f32x4 sv = (f32x4){0.f, 0.f, 0.f, 0.f};
            #pragma unroll
            for (int kc = 0; kc < 2; ++kc) {
                bf16x8 kf = *(const bf16x8*)(Ks + krow * 64 + (((kc * 4 + g) ^ (fr & 7)) << 3));
                sv = __builtin_amdgcn_mfma_f32_16x16x32_bf16(qf[kc], kf, sv, 0, 0, 0);
            }
            s[jf] = sv;
        }
        __builtin_amdgcn_s_setprio(0);
        if (kt == last) {
            #pragma unroll
            for (int jf = 0; jf < 4; ++jf) {
                const int k = k0 + jf * 16 + fr;
                #pragma unroll
                for (int r = 0; r < 4; ++r) {
                    const int q = q0w + g * 4 + r;
                    if (k > q) s[jf][r] = -1e30f;
                }
            }
        }

        #pragma unroll
        for (int r = 0; r < 4; ++r) {
            float mx = fmaxf(fmaxf(s[0][r], s[1][r]), fmaxf(s[2][r], s[3][r]));
            mx = fmaxf(mx, __shfl_xor(mx, 1));
            mx = fmaxf(mx, __shfl_xor(mx, 2));
            mx = fmaxf(mx, __shfl_xor(mx, 4));
            mx = fmaxf(mx, __shfl_xor(mx, 8));
            const float mn = fmaxf(m[r], mx);
            const float sc2 = __expf(m[r] - mn);
            m[r] = mn;
            float rs = 0.f;
            #pragma unroll
            for (int jf = 0; jf < 4; ++jf) {
                const float p = __expf(s[jf][r] - mn);
                s[jf][r] = p;
                rs += p;
            }
            rs += __shfl_xor(rs, 1);
            rs += __shfl_xor(rs, 2);
            rs += __shfl_xor(rs, 4);
            rs += __shfl_xor(rs, 8);
            l[r] = l[r] * sc2 + rs;
            #pragma unroll
            for (int jd = 0; jd < 4; ++jd) acc[jd][r] *= sc2;
        }

        __bf16* pw = &Ps[w][0];
        #pragma unroll
        for (int jf = 0; jf < 4; ++jf) {
            const int chp = jf * 2 + (fr >> 3);
            #pragma unroll
            for (int r = 0; r < 4; ++r) {
                const int row = g * 4 + r;
                pw[row * 64 + (((chp ^ (row & 7)) << 3) + (fr & 7))] = (__bf16)s[jf][r];
            }
        }
        asm volatile("s_waitcnt lgkmcnt(0)" ::: "memory");
        bf16x8 pa[2];
        #pragma unroll
        for (int kc = 0; kc < 2; ++kc)
            pa[kc] = *(const bf16x8*)(pw + fr * 64 + (((kc * 4 + g) ^ (fr & 7)) << 3));

        __builtin_amdgcn_s_setprio(1);
        #pragma unroll
        for (int jd = 0; jd < 4; ++jd) {
            const int d = jd * 16 + fr;
            const int key = ((d >> 3) ^ d) & 7;
            #pragma unroll
            for (int kc = 0; kc < 2; ++kc) {
                bf16x8 vf = *(const bf16x8*)(Vt + d * 64 + (((kc * 4 + g) ^ key) << 3));
                acc[jd] = __builtin_amdgcn_mfma_f32_16x16x32_bf16(pa[kc], vf, acc[jd], 0, 0, 0);
            }
        }
        __builtin_amdgcn_s_setprio(0);

        if (kt < last) {
            __syncthreads();
            #pragma unroll
            for (int it = 0; it < 4; ++it) {
                const int row = it * 16 + r0;
                *(bf16x8*)(Ks + row * 64 + ((ch ^ (row & 7)) << 3)) = kr[it];
                #pragma unroll
                for (int j = 0; j < 8; ++j) {
                    const int d = ch * 8 + j;
                    const int key = ((d >> 3) ^ d) & 7;
                    Vt[d * 64 + ((((row >> 3) ^ key) << 3) + (row & 7))] = vr[it][j];
                }
            }
            __syncthreads();
        }
    }

    #pragma unroll
    for (int r = 0; r < 4; ++r) {
        const float inv = 1.0f / l[r];
        const int q = q0w + g * 4 + r;
        __bf16* yp = y + ((size_t)(b * TDIM + q)) * EDIM + h * 64;
        #pragma unroll
        for (int jd = 0; jd < 4; ++jd)
            yp[jd * 16 + fr] = (__bf16)(acc[jd][r] * inv);
    }
}

// ---------------------------------------------------------------- fused-LSE finalize
__global__ __launch_bounds__(256) void lsefin_kernel(
    const float* __restrict__ part, const float* __restrict__ logits,
    const int* __restrict__ targets, float* __restrict__ rr)
{
    const int row = blockIdx.x, tid = threadIdx.x;
    float s = 0.f;
    for (int j = tid; j < NPB; j += 256) s += part[(size_t)row * NPB + j];
    #pragma unroll
    for (int off = 32; off; off >>= 1) s += __shfl_xor(s, off);
    __shared__ float red[4];
    if ((tid & 63) == 0) red[tid >> 6] = s;
    __syncthreads();
    if (tid == 0) {
        float S = red[0] + red[1] + red[2] + red[3];
        rr[row] = logf(S) - logits[(size_t)row * VDIM + targets[row]];
    }
}

__global__ __launch_bounds__(256) void loss_reduce_kernel(
    const float* __restrict__ rr, float* __restrict__ out)
{
    const int tid = threadIdx.x;
    float s = 0.f;
    for (int i = tid; i < BT; i += 256) s += rr[i];
    #pragma unroll
    for (int off = 32; off; off >>= 1) s += __shfl_xor(s, off);
    __shared__ float red[4];
    if ((tid & 63) == 0) red[tid >> 6] = s;
    __syncthreads();
    if (tid == 0) out[0] = (red[0] + red[1] + red[2] + red[3]) * (1.0f / BT);
}

// ---------------------------------------------------------------- launch
extern "C" void kernel_launch(void* const* d_in, const int* in_sizes, int n_in,
                              void* d_out, int out_size, void* d_ws, size_t ws_size,
                              hipStream_t stream)
{
    const int*   idx     = (const int*)d_in[0];
    const int*   targets = (const int*)d_in[1];
    const float* wte     = (const float*)d_in[2];
    const float* wpe     = (const float*)d_in[3];
    const float* ln1_w   = (const float*)d_in[4];
    const float* ln1_b   = (const float*)d_in[5];
    const float* attn_w  = (const float*)d_in[6];
    const float* attn_b  = (const float*)d_in[7];
    const float* proj_w  = (const float*)d_in[8];
    const float* proj_b  = (const float*)d_in[9];
    const float* ln2_w   = (const float*)d_in[10];
    const float* ln2_b   = (const float*)d_in[11];
    const float* fc_w    = (const float*)d_in[12];
    const float* fc_b    = (const float*)d_in[13];
    const float* fcp_w   = (const float*)d_in[14];
    const float* fcp_b   = (const float*)d_in[15];
    const float* lnf_w   = (const float*)d_in[16];
    const float* lnf_b   = (const float*)d_in[17];

    float* logits = (float*)d_out;

    const size_t slq = (size_t)EDIM * E3, slp = (size_t)EDIM * EDIM;
    const size_t slf = (size_t)EDIM * E4, slfp = (size_t)E4 * EDIM;

    char* wp = (char*)d_ws;
    float*  x     = (float*)wp;   wp += (size_t)BT * EDIM * 4;
    __bf16* qkvb  = (__bf16*)wp;  wp += (size_t)BT * E3 * 2;
    __bf16* xnbf  = (__bf16*)wp;  wp += (size_t)BT * EDIM * 2;
    __bf16* ybf   = (__bf16*)wp;  wp += (size_t)BT * EDIM * 2;
    __bf16* hbf   = (__bf16*)wp;  wp += (size_t)BT * E4 * 2;
    __bf16* wteb  = (__bf16*)wp;  wp += (size_t)VDIM * EDIM * 2;
    float*  part  = (float*)wp;   wp += (size_t)BT * NPB * 4;
    float*  psum  = (float*)wp;   wp += (size_t)2 * BT * EDIM * 4;
    float*  rr    = (float*)wp;   wp += (size_t)BT * 4;
    __bf16* wqkvb = (__bf16*)wp;

    const size_t wbytes_all = (slq + slp + slf + slfp) * 2 * LNUM;
    const size_t used = (size_t)(wp - (char*)d_ws);
    const bool big = ws_size >= used + wbytes_all;
    const size_t L = big ? LNUM : 1;
    __bf16* wprjb = wqkvb + slq * L;
    __bf16* wfcb  = wprjb + slp * L;
    __bf16* wfpb  = wfcb  + slf * L;

    embed_kernel<<<BT, 256, 0, stream>>>(idx, wte, wpe, x);
    cvt_kernel<<<2048, 256, 0, stream>>>(wte, wteb, (long)VDIM * EDIM / 4);

    if (big) {
        convt_kernel<<<dim3(E3 / 32, EDIM / 32, LNUM), 256, 0, stream>>>(attn_w, wqkvb, EDIM, E3);
        convt_kernel<<<dim3(EDIM / 32, EDIM / 32, LNUM), 256, 0, stream>>>(proj_w, wprjb, EDIM, EDIM);
        convt_kernel<<<dim3(E4 / 32, EDIM / 32, LNUM), 256, 0, stream>>>(fc_w, wfcb, EDIM, E4);
        convt_kernel<<<dim3(EDIM / 32, E4 / 32, LNUM), 256, 0, stream>>>(fcp_w, wfpb, E4, EDIM);
    }

    ln_kernel<<<BT / 4, 256, 0, stream>>>(x, ln1_w, ln1_b, xnbf);

    for (int l = 0; l < LNUM; ++l) {
        const __bf16* wq = wqkvb + (big ? (size_t)l * slq : 0);
        const __bf16* wpj = wprjb + (big ? (size_t)l * slp : 0);
        const __bf16* wf = wfcb + (big ? (size_t)l * slf : 0);
        const __bf16* wfp = wfpb + (big ? (size_t)l * slfp : 0);

        if (!big)
            convt_kernel<<<dim3(E3 / 32, EDIM / 32), 256, 0, stream>>>(
                attn_w + (size_t)l * slq, (__bf16*)wq, EDIM, E3);
        mgemm<64, 64, 64, true, false, false, true, false>
            <<<dim3(E3 / 64, BT / 64), 256, 0, stream>>>(
            xnbf, wq, attn_b + (size_t)l * E3, nullptr, qkvb, BT, E3, EDIM, EDIM);
        fattn_kernel<<<dim3(TDIM / 32, HNUM, BDIM), 128, 0, stream>>>(qkvb, ybf);
        if (!big)
            convt_kernel<<<dim3(EDIM / 32, EDIM / 32), 256, 0, stream>>>(
                proj_w + (size_t)l * slp, (__bf16*)wpj, EDIM, EDIM);
        mgemm<64, 64, 64, false, false, false, false, false>
            <<<dim3(EDIM / 64, BT / 64, 2), 256, 0, stream>>>(
            ybf, wpj, nullptr, nullptr, psum, BT, EDIM, EDIM / 2, EDIM);
        redln_kernel<<<BT / 4, 256, 0, stream>>>(
            psum, proj_b + (size_t)l * EDIM, x,
            ln2_w + (size_t)l * EDIM, ln2_b + (size_t)l * EDIM, xnbf);
        if (!big)
            convt_kernel<<<dim3(E4 / 32, EDIM / 32), 256, 0, stream>>>(
                fc_w + (size_t)l * slf, (__bf16*)wf, EDIM, E4);
        mgemm<64, 64, 64, true, true, false, true, false>
            <<<dim3(E4 / 64, BT / 64), 256, 0, stream>>>(
            xnbf, wf, fc_b + (size_t)l * E4, nullptr, hbf, BT, E4, EDIM, EDIM);
        if (!big)
            convt_kernel<<<dim3(EDIM / 32, E4 / 32), 256, 0, stream>>>(
                fcp_w + (size_t)l * slfp, (__bf16*)wfp, E4, EDIM);
        mgemm<64, 64, 64, false, false, false, false, false>
            <<<dim3(EDIM / 64, BT / 64, 2), 256, 0, stream>>>(
            hbf, wfp, nullptr, nullptr, psum, BT, EDIM, E4 / 2, E4);
        const float* nw = (l + 1 < LNUM) ? ln1_w + (size_t)(l + 1) * EDIM : lnf_w;
        const float* nb = (l + 1 < LNUM) ? ln1_b + (size_t)(l + 1) * EDIM : lnf_b;
        redln_kernel<<<BT / 4, 256, 0, stream>>>(
            psum, fcp_b + (size_t)l * EDIM, x, nw, nb, xnbf);
    }

    lgemm<<<dim3(64 * 50), 512, 0, stream>>>(
        xnbf, wteb, logits, part, BT, VDIM, EDIM);
    lsefin_kernel<<<BT, 256, 0, stream>>>(part, logits, targets, rr);
    loss_reduce_kernel<<<1, 256, 0, stream>>>(rr, logits + (size_t)BT * VDIM);
}

// Round 18
// 1969.811 us; speedup vs baseline: 1.0592x; 1.0592x over previous
//
#include <hip/hip_runtime.h>
#include <hip/hip_bf16.h>
#include <math.h>

#define LNUM 12
#define HNUM 12
#define EDIM 768
#define VDIM 50257
#define BDIM 2
#define TDIM 1024
#define BT (BDIM*TDIM)
#define E3 (3*EDIM)
#define E4 (4*EDIM)
#define NPB (2*((VDIM+127)/128))   // 786 per-64-col partials per row

typedef __bf16 bf16x8 __attribute__((ext_vector_type(8)));
typedef __bf16 bf16x4 __attribute__((ext_vector_type(4)));
typedef float f32x4 __attribute__((ext_vector_type(4)));

__device__ __forceinline__ float gelu_f(float x) {
    float u = 0.7978845608028654f * (x + 0.044715f * x * x * x);
    return 0.5f * x * (1.0f + tanhf(u));
}

// async global->LDS, 16B per lane
__device__ __forceinline__ void gl16(const void* g, void* l) {
    __builtin_amdgcn_global_load_lds(
        (const __attribute__((address_space(1))) unsigned int*)g,
        (__attribute__((address_space(3))) unsigned int*)l,
        16, 0, 0);
}

// ---------------------------------------------------------------- embedding
__global__ __launch_bounds__(256) void embed_kernel(
    const int* __restrict__ idx, const float* __restrict__ wte,
    const float* __restrict__ wpe, float* __restrict__ x)
{
    const int row = blockIdx.x;
    const int t = row % TDIM;
    const int tok = idx[row];
    const float* we = wte + (size_t)tok * EDIM;
    const float* pe = wpe + (size_t)t * EDIM;
    float* xr = x + (size_t)row * EDIM;
    for (int e = threadIdx.x; e < EDIM; e += 256) xr[e] = we[e] + pe[e];
}

// ---------------------------------------------------------------- layernorm (bf16 out)
__global__ __launch_bounds__(256) void ln_kernel(
    const float* __restrict__ in, const float* __restrict__ w,
    const float* __restrict__ b, __bf16* __restrict__ out)
{
    const int row = blockIdx.x * 4 + (threadIdx.x >> 6);
    const int lane = threadIdx.x & 63;
    const float4* xr = (const float4*)(in + (size_t)row * EDIM);
    float4 a0 = xr[lane], a1 = xr[64 + lane], a2 = xr[128 + lane];
    float s = a0.x + a0.y + a0.z + a0.w + a1.x + a1.y + a1.z + a1.w
            + a2.x + a2.y + a2.z + a2.w;
    #pragma unroll
    for (int off = 32; off; off >>= 1) s += __shfl_xor(s, off);
    const float mean = s * (1.0f / EDIM);
    float4 d0 = make_float4(a0.x - mean, a0.y - mean, a0.z - mean, a0.w - mean);
    float4 d1 = make_float4(a1.x - mean, a1.y - mean, a1.z - mean, a1.w - mean);
    float4 d2 = make_float4(a2.x - mean, a2.y - mean, a2.z - mean, a2.w - mean);
    float v = d0.x*d0.x + d0.y*d0.y + d0.z*d0.z + d0.w*d0.w
            + d1.x*d1.x + d1.y*d1.y + d1.z*d1.z + d1.w*d1.w
            + d2.x*d2.x + d2.y*d2.y + d2.z*d2.z + d2.w*d2.w;
    #pragma unroll
    for (int off = 32; off; off >>= 1) v += __shfl_xor(v, off);
    const float inv = rsqrtf(v * (1.0f / EDIM) + 1e-5f);
    const float4* w4 = (const float4*)w;
    const float4* b4 = (const float4*)b;
    __bf16* orow = out + (size_t)row * EDIM;
    #pragma unroll
    for (int c = 0; c < 3; ++c) {
        float4 dd = c == 0 ? d0 : (c == 1 ? d1 : d2);
        float4 ww = w4[c * 64 + lane], bb = b4[c * 64 + lane];
        bf16x4 o;
        o[0] = (__bf16)(dd.x * inv * ww.x + bb.x);
        o[1] = (__bf16)(dd.y * inv * ww.y + bb.y);
        o[2] = (__bf16)(dd.z * inv * ww.z + bb.z);
        o[3] = (__bf16)(dd.w * inv * ww.w + bb.w);
        *(bf16x4*)(orow + c * 256 + lane * 4) = o;
    }
}

// ------------------------------------------- split-K reduce + bias + residual + LN
__global__ __launch_bounds__(256) void redln_kernel(
    const float* __restrict__ ps, const float* __restrict__ bias,
    float* __restrict__ x, const float* __restrict__ w,
    const float* __restrict__ b, __bf16* __restrict__ out)
{
    const int row = blockIdx.x * 4 + (threadIdx.x >> 6);
    const int lane = threadIdx.x & 63;
    const float4* p0 = (const float4*)(ps + (size_t)row * EDIM);
    const float4* p1 = (const float4*)(ps + (size_t)(BT + row) * EDIM);
    float4* xr = (float4*)(x + (size_t)row * EDIM);
    const float4* b4 = (const float4*)bias;
    float4 a[3];
    #pragma unroll
    for (int c = 0; c < 3; ++c) {
        const int i = c * 64 + lane;
        float4 u = p0[i], v = p1[i], xx = xr[i], bb = b4[i];
        a[c] = make_float4(u.x + v.x + xx.x + bb.x, u.y + v.y + xx.y + bb.y,
                           u.z + v.z + xx.z + bb.z, u.w + v.w + xx.w + bb.w);
        xr[i] = a[c];
    }
    float s = a[0].x + a[0].y + a[0].z + a[0].w + a[1].x + a[1].y + a[1].z + a[1].w
            + a[2].x + a[2].y + a[2].z + a[2].w;
    #pragma unroll
    for (int off = 32; off; off >>= 1) s += __shfl_xor(s, off);
    const float mean = s * (1.0f / EDIM);
    float v = 0.f;
    #pragma unroll
    for (int c = 0; c < 3; ++c) {
        a[c] = make_float4(a[c].x - mean, a[c].y - mean, a[c].z - mean, a[c].w - mean);
        v += a[c].x * a[c].x + a[c].y * a[c].y + a[c].z * a[c].z + a[c].w * a[c].w;
    }
    #pragma unroll
    for (int off = 32; off; off >>= 1) v += __shfl_xor(v, off);
    const float inv = rsqrtf(v * (1.0f / EDIM) + 1e-5f);
    const float4* w4 = (const float4*)w;
    const float4* lb4 = (const float4*)b;
    __bf16* orow = out + (size_t)row * EDIM;
    #pragma unroll
    for (int c = 0; c < 3; ++c) {
        float4 ww = w4[c * 64 + lane], bb = lb4[c * 64 + lane];
        bf16x4 o;
        o[0] = (__bf16)(a[c].x * inv * ww.x + bb.x);
        o[1] = (__bf16)(a[c].y * inv * ww.y + bb.y);
        o[2] = (__bf16)(a[c].z * inv * ww.z + bb.z);
        o[3] = (__bf16)(a[c].w * inv * ww.w + bb.w);
        *(bf16x4*)(orow + c * 256 + lane * 4) = o;
    }
}

// ------------------------------------------------- weight convert: f32 [K][N] -> bf16 [N][K]
__global__ __launch_bounds__(256) void convt_kernel(
    const float* __restrict__ in, __bf16* __restrict__ out, int K, int N)
{
    in  += (size_t)blockIdx.z * K * N;
    out += (size_t)blockIdx.z * K * N;
    __shared__ float t[32][33];
    const int n0 = blockIdx.x * 32, k0 = blockIdx.y * 32;
    const int r = threadIdx.x >> 3, c = (threadIdx.x & 7) * 4;
    float4 v = *(const float4*)(in + (size_t)(k0 + r) * N + n0 + c);
    t[r][c + 0] = v.x; t[r][c + 1] = v.y; t[r][c + 2] = v.z; t[r][c + 3] = v.w;
    __syncthreads();
    bf16x4 o;
    o[0] = (__bf16)t[c + 0][r];
    o[1] = (__bf16)t[c + 1][r];
    o[2] = (__bf16)t[c + 2][r];
    o[3] = (__bf16)t[c + 3][r];
    *(bf16x4*)(out + (size_t)(n0 + r) * K + k0 + c) = o;
}

// ------------------------------------------------- elementwise f32 -> bf16 (wte)
__global__ __launch_bounds__(256) void cvt_kernel(
    const float* __restrict__ in, __bf16* __restrict__ out, long n4)
{
    for (long i = blockIdx.x * 256L + threadIdx.x; i < n4; i += (long)gridDim.x * 256L) {
        float4 v = ((const float4*)in)[i];
        out[i * 4 + 0] = (__bf16)v.x;
        out[i * 4 + 1] = (__bf16)v.y;
        out[i * 4 + 2] = (__bf16)v.z;
        out[i * 4 + 3] = (__bf16)v.w;
    }
}

// ---------------------------------------------------------------- MFMA GEMM (layer GEMMs)
template<int BM, int BN, int BK, bool BIAS, bool GELU_, bool RES_, bool OUTBF, bool NGUARD>
__global__ __launch_bounds__(256, 2) void mgemm(
    const __bf16* __restrict__ A, const __bf16* __restrict__ Bt,
    const float* __restrict__ bias, const float* __restrict__ res,
    void* __restrict__ Cout, int M, int N, int K, int lda)
{
    constexpr int WM = BM / 2, WN = BN / 2;
    constexpr int FM = WM / 16, FN = WN / 16;
    constexpr int KS = BK / 32;
    constexpr int TBA = BM * BK * 2;
    constexpr int TBB = BN * BK * 2;
    constexpr int rA = TBA / 4096, rB = TBB / 4096;
    constexpr int RPI = 2048 / BK;
    constexpr int CPR = BK / 8;
    __shared__ __align__(16) __bf16 As[3 * BM * BK];
    __shared__ __align__(16) __bf16 Bs[3 * BN * BK];
    const int tid = threadIdx.x;
    const int lane = tid & 63;
    const int wave = tid >> 6;
    const int wr = wave >> 1, wc = wave & 1;

    const int bm = blockIdx.y, bn = blockIdx.x;
    const int m0 = bm * BM;
    const int n0 = bn * BN;
    const int kbase = blockIdx.z * K;
    const size_t zoff = (size_t)blockIdx.z * M * N;

    const int srow = tid / CPR;
    const int skey = (BK == 32) ? ((srow >> 1) & 3) : (srow & 7);
    const int c0 = (tid % CPR) ^ skey;

    const __bf16* gA = A + (size_t)(m0 + srow) * lda + kbase + c0 * 8;
    const __bf16* gB[rB];
    #pragma unroll
    for (int r = 0; r < rB; ++r) {
        int nr = n0 + srow + r * RPI;
        if (NGUARD) nr = nr < N ? nr : N - 1;
        gB[r] = Bt + (size_t)nr * lda + kbase + c0 * 8;
    }

    const int fr = lane & 15;
    const int g = lane >> 4;
    const int fkey = (BK == 32) ? ((fr >> 1) & 3) : (fr & 7);

    f32x4 acc[FM][FN];
    #pragma unroll
    for (int i = 0; i < FM; i++)
        #pragma unroll
        for (int j = 0; j < FN; j++) acc[i][j] = (f32x4){0.f, 0.f, 0.f, 0.f};

    const int nt = K / BK;

    auto stage = [&](int kk, int b) {
        #pragma unroll
        for (int r = 0; r < rA; ++r)
            gl16(gA + (size_t)r * RPI * lda + kk, (char*)As + b * TBA + r * 4096 + tid * 16);
        #pragma unroll
        for (int r = 0; r < rB; ++r)
            gl16(gB[r] + kk, (char*)Bs + b * TBB + r * 4096 + tid * 16);
    };

    stage(0, 0);
    if (nt > 1) stage(BK, 1);

    int b0 = 0, b1 = 1, b2 = 2;
    for (int t = 0; t < nt; ++t) {
        if (t + 1 < nt) {
            static_assert(rA + rB == 4 || rA + rB == 6, "vmcnt literal");
            if constexpr (rA + rB == 4) asm volatile("s_waitcnt vmcnt(4)" ::: "memory");
            else                        asm volatile("s_waitcnt vmcnt(6)" ::: "memory");
        } else {
            asm volatile("s_waitcnt vmcnt(0)" ::: "memory");
        }
        asm volatile("s_barrier" ::: "memory");
        if (t + 2 < nt) stage((t + 2) * BK, b2);

        const char* pa = (const char*)As + b0 * TBA;
        const char* pb = (const char*)Bs + b0 * TBB;
        bf16x8 af[FM][KS], bfr[FN][KS];
        #pragma unroll
        for (int i = 0; i < FM; i++)
            #pragma unroll
            for (int kc = 0; kc < KS; kc++)
                af[i][kc] = *(const bf16x8*)(pa + (wr * WM + i * 16 + fr) * (2 * BK)
                                                + (((kc * 4 + g) ^ fkey) << 4));
        #pragma unroll
        for (int j = 0; j < FN; j++)
            #pragma unroll
            for (int kc = 0; kc < KS; kc++)
                bfr[j][kc] = *(const bf16x8*)(pb + (wc * WN + j * 16 + fr) * (2 * BK)
                                                 + (((kc * 4 + g) ^ fkey) << 4));
        #pragma unroll
        for (int kc = 0; kc < KS; kc++)
            #pragma unroll
            for (int i = 0; i < FM; i++)
                #pragma unroll
                for (int j = 0; j < FN; j++)
                    acc[i][j] = __builtin_amdgcn_mfma_f32_16x16x32_bf16(af[i][kc], bfr[j][kc], acc[i][j], 0, 0, 0);
        const int tmp = b0; b0 = b1; b1 = b2; b2 = tmp;
    }

    const int crow = g * 4;
    #pragma unroll
    for (int i = 0; i < FM; i++) {
        #pragma unroll
        for (int r = 0; r < 4; r++) {
            const int m = m0 + wr * WM + i * 16 + crow + r;
            #pragma unroll
            for (int j = 0; j < FN; j++) {
                const int n = n0 + wc * WN + j * 16 + fr;
                if (!NGUARD || n < N) {
                    float v = acc[i][j][r];
                    if (BIAS) v += bias[n];
                    if (GELU_) v = gelu_f(v);
                    if (RES_) v += res[(size_t)m * N + n];
                    if (OUTBF) ((__bf16*)Cout)[zoff + (size_t)m * N + n] = (__bf16)v;
                    else       ((float*)Cout)[zoff + (size_t)m * N + n] = v;
                }
            }
        }
    }
}

// ---------------------------------------------------------------- logits GEMM (phase-interleaved)
// R15 config (best measured): 512 threads (8 waves, 4M x 2N), BM=256 BN=128
// BK=64, 3 LDS buffers, ONE barrier per K-tile, counted vmcnt(6), 2 phases/tile.
__global__ __launch_bounds__(512, 1) void lgemm(
    const __bf16* __restrict__ A, const __bf16* __restrict__ Bt,
    float* __restrict__ Cout, float* __restrict__ part, int M, int N, int K)
{
    __shared__ __align__(16) __bf16 As[3 * 256 * 64];   // 96 KB
    __shared__ __align__(16) __bf16 Bs[3 * 128 * 64];   // 48 KB
    const int tid = threadIdx.x;
    const int lane = tid & 63;
    const int wave = tid >> 6;
    const int wm = wave >> 1, wn = wave & 1;

    const int wg = blockIdx.x;
    const int bm = (wg >> 3) & 7;
    const int bn = (wg & 7) + ((wg >> 6) << 3);
    if (bn * 128 >= N) return;
    const int m0 = bm * 256, n0 = bn * 128;

    const int srow = tid >> 3;
    const int c0 = (tid & 7) ^ (srow & 7);
    const __bf16* gA = A + (size_t)(m0 + srow) * K + c0 * 8;
    const __bf16* gB[2];
    #pragma unroll
    for (int r = 0; r < 2; ++r) {
        int nr = n0 + r * 64 + srow;
        nr = nr < N ? nr : N - 1;
        gB[r] = Bt + (size_t)nr * K + c0 * 8;
    }

    const int fr = lane & 15;
    const int g = lane >> 4;
    const int fk = fr & 7;

    auto stageA = [&](int kk, int b, int r) {
        gl16(gA + (size_t)r * 64 * K + kk, (char*)As + b * 32768 + r * 8192 + tid * 16);
    };
    auto stageB = [&](int kk, int b, int r) {
        gl16(gB[r] + kk, (char*)Bs + b * 16384 + r * 8192 + tid * 16);
    };

    f32x4 acc[4][4];
    #pragma unroll
    for (int i = 0; i < 4; i++)
        #pragma unroll
        for (int j = 0; j < 4; j++) acc[i][j] = (f32x4){0.f, 0.f, 0.f, 0.f};

    const int nt = K >> 6;   // 12
    #pragma unroll
    for (int r = 0; r < 4; ++r) stageA(0, 0, r);
    #pragma unroll
    for (int r = 0; r < 2; ++r) stageB(0, 0, r);
    #pragma unroll
    for (int r = 0; r < 4; ++r) stageA(64, 1, r);
    #pragma unroll
    for (int r = 0; r < 2; ++r) stageB(64, 1, r);

    for (int t = 0; t < nt; ++t) {
        const int bt = t % 3;
        if (t + 1 < nt) asm volatile("s_waitcnt vmcnt(6)" ::: "memory");
        else            asm volatile("s_waitcnt vmcnt(0)" ::: "memory");
        asm volatile("s_barrier" ::: "memory");

        const char* pa = (const char*)As + bt * 32768;
        const char* pb = (const char*)Bs + bt * 16384;
        const int kk2 = (t + 2) * 64;
        const int b2 = (t + 2) % 3;

        bf16x8 bfr[4][2], af[2][2];
        #pragma unroll
        for (int j = 0; j < 4; ++j)
            #pragma unroll
            for (int kc = 0; kc < 2; ++kc)
                bfr[j][kc] = *(const bf16x8*)(pb + (wn * 64 + j * 16 + fr) * 128
                                                 + (((kc * 4 + g) ^ fk) << 4));
        #pragma unroll
        for (int i = 0; i < 2; ++i)
            #pragma unroll
            for (int kc = 0; kc < 2; ++kc)
                af[i][kc] = *(const bf16x8*)(pa + (wm * 64 + i * 16 + fr) * 128
                                                + (((kc * 4 + g) ^ fk) << 4));
        if (t + 2 < nt) { stageA(kk2, b2, 0); stageA(kk2, b2, 1); stageA(kk2, b2, 2); }
        __builtin_amdgcn_s_setprio(1);
        #pragma unroll
        for (int kc = 0; kc < 2; ++kc)
            #pragma unroll
            for (int i = 0; i < 2; ++i)
                #pragma unroll
                for (int j = 0; j < 4; ++j)
                    acc[i][j] = __builtin_amdgcn_mfma_f32_16x16x32_bf16(af[i][kc], bfr[j][kc], acc[i][j], 0, 0, 0);
        __builtin_amdgcn_s_setprio(0);

        bf16x8 af1[2][2];
        #pragma unroll
        for (int i = 0; i < 2; ++i)
            #pragma unroll
            for (int kc = 0; kc < 2; ++kc)
                af1[i][kc] = *(const bf16x8*)(pa + (wm * 64 + (i + 2) * 16 + fr) * 128
                                                 + (((kc * 4 + g) ^ fk) << 4));
        if (t + 2 < nt) { stageA(kk2, b2, 3); stageB(kk2, b2, 0); stageB(kk2, b2, 1); }
        __builtin_amdgcn_s_setprio(1);
        #pragma unroll
        for (int kc = 0; kc < 2; ++kc)
            #pragma unroll
            for (int i = 0; i < 2; ++i)
                #pragma unroll
                for (int j = 0; j < 4; ++j)
                    acc[i + 2][j] = __builtin_amdgcn_mfma_f32_16x16x32_bf16(af1[i][kc], bfr[j][kc], acc[i + 2][j], 0, 0, 0);
        __builtin_amdgcn_s_setprio(0);
    }

    // epilogue: f32 stores + per-64-col sum-exp partials
    const int crow = g * 4;
    const int cg = bn * 2 + wn;
    #pragma unroll
    for (int i = 0; i < 4; i++) {
        #pragma unroll
        for (int r = 0; r < 4; r++) {
            const int m = m0 + wm * 64 + i * 16 + crow + r;
            float se = 0.f;
            #pragma unroll
            for (int j = 0; j < 4; j++) {
                const int n = n0 + wn * 64 + j * 16 + fr;
                if (n < N) {
                    float v = acc[i][j][r];
                    Cout[(size_t)m * N + n] = v;
                    se += __expf(v);
                }
            }
            se += __shfl_xor(se, 1); se += __shfl_xor(se, 2);
            se += __shfl_xor(se, 4); se += __shfl_xor(se, 8);
            if (fr == 0 && (n0 + wn * 64) < N)
                part[(size_t)m * NPB + cg] = se;
        }
    }
}

// ---------------------------------------------------------------- flash attention (bf16 MFMA)
__global__ __launch_bounds__(128) void fattn_kernel(
    const __bf16* __restrict__ qkv, __bf16* __restrict__ y)
{
    const int bq = gridDim.x - 1 - blockIdx.x;
    const int h = blockIdx.y, b = blockIdx.z;
    const int tid = threadIdx.x, lane = tid & 63, w = tid >> 6;
    const int fr = lane & 15, g = lane >> 4;

    __shared__ __align__(16) __bf16 Ks[64 * 64];
    __shared__ __align__(16) __bf16 Vt[64 * 64];
    __shared__ __align__(16) __bf16 Ps[2][16 * 64];

    const __bf16* base = qkv + (size_t)b * TDIM * E3;
    const int q0w = bq * 32 + w * 16;
    const int NT = (bq >> 1) + 1;
    const int last = NT - 1;

    bf16x8 qf[2];
    {
        const __bf16* qp = base + (size_t)(q0w + fr) * E3 + h * 64 + g * 8;
        qf[0] = *(const bf16x8*)qp;
        qf[1] = *(const bf16x8*)(qp + 32);
        const __bf16 sc = (__bf16)0.125f;   // exact (power of two)
        #pragma unroll
        for (int e = 0; e < 8; ++e) { qf[0][e] *= sc; qf[1][e] *= sc; }
    }

    const int r0 = tid >> 3, ch = tid & 7;
    bf16x8 kr[4], vr[4];

    #pragma unroll
    for (int it = 0; it < 4; ++it) {
        const int row = it * 16 + r0;
        const __bf16* gp = base + (size_t)row * E3 + EDIM + h * 64 + ch * 8;
        kr[it] = *(const bf16x8*)gp;
        vr[it] = *(const bf16x8*)(gp + EDIM);
    }
    #pragma unroll
    for (int it = 0; it < 4; ++it) {
        const int row = it * 16 + r0;
        *(bf16x8*)(Ks + row * 64 + ((ch ^ (row & 7)) << 3)) = kr[it];
        #pragma unroll
        for (int j = 0; j < 8; ++j) {
            const int d = ch * 8 + j;
            const int key = ((d >> 3) ^ d) & 7;
            Vt[d * 64 + ((((row >> 3) ^ key) << 3) + (row & 7))] = vr[it][j];
        }
    }
    __syncthreads();

    float m[4] = {-1e30f, -1e30f, -1e30f, -1e30f};
    float l[4] = {0.f, 0.f, 0.f, 0.f};
    f32x4 acc[4];
    #pragma unroll
    for (int jd = 0; jd < 4; ++jd) acc[jd] = (f32x4){0.f, 0.f, 0.f, 0.f};

    for (int kt = 0; kt < NT; ++kt) {
        if (kt < last) {
            const int k1 = (kt + 1) * 64;
            #pragma unroll
            for (int it = 0; it < 4; ++it) {
                const int row = it * 16 + r0;
                const __bf16* gp = base + (size_t)(k1 + row) * E3 + EDIM + h * 64 + ch * 8;
                kr[it] = *(const bf16x8*)gp;
                vr[it] = *(const bf16x8*)(gp + EDIM);
            }
        }

        const int k0 = kt * 64;
        f32x4 s[4];
        __builtin_amdgcn_s_setprio(1);
        #pragma unroll
        for (int jf = 0; jf < 4; ++jf) {
            const int krow = jf * 16 + fr;
            f32x4 sv = (f32x4){0.f, 0.f, 0.f, 0.f};
            #pragma unroll
            for (int kc = 0; kc < 2; ++kc) {
                bf16x8 kf = *(const bf16x8*)(Ks + krow * 64 + (((kc * 4 + g) ^ (fr & 7)) << 3));
                sv = __builtin_amdgcn_mfma_f32_16x16x32_bf16(qf[kc], kf, sv, 0, 0, 0);
            }
            s[jf] = sv;
        }
        __builtin_amdgcn_s_setprio(0);
        if (kt == last) {
            #pragma unroll
            for (int jf = 0; jf < 4; ++jf) {
                const int k = k0 + jf * 16 + fr;
                #pragma unroll
                for (int r = 0; r < 4; ++r) {
                    const int q = q0w + g * 4 + r;
                    if (k > q) s[jf][r] = -1e30f;
                }
            }
        }

        #pragma unroll
        for (int r = 0; r < 4; ++r) {
            float mx = fmaxf(fmaxf(s[0][r], s[1][r]), fmaxf(s[2][r], s[3][r]));
            mx = fmaxf(mx, __shfl_xor(mx, 1));
            mx = fmaxf(mx, __shfl_xor(mx, 2));
            mx = fmaxf(mx, __shfl_xor(mx, 4));
            mx = fmaxf(mx, __shfl_xor(mx, 8));
            const float mn = fmaxf(m[r], mx);
            const float sc2 = __expf(m[r] - mn);
            m[r] = mn;
            float rs = 0.f;
            #pragma unroll
            for (int jf = 0; jf < 4; ++jf) {
                const float p = __expf(s[jf][r] - mn);
                s[jf][r] = p;
                rs += p;
            }
            rs += __shfl_xor(rs, 1);
            rs += __shfl_xor(rs, 2);
            rs += __shfl_xor(rs, 4);
            rs += __shfl_xor(rs, 8);
            l[r] = l[r] * sc2 + rs;
            #pragma unroll
            for (int jd = 0; jd < 4; ++jd) acc[jd][r] *= sc2;
        }

        __bf16* pw = &Ps[w][0];
        #pragma unroll
        for (int jf = 0; jf < 4; ++jf) {
            const int chp = jf * 2 + (fr >> 3);
            #pragma unroll
            for (int r = 0; r < 4; ++r) {
                const int row = g * 4 + r;
                pw[row * 64 + (((chp ^ (row & 7)) << 3) + (fr & 7))] = (__bf16)s[jf][r];
            }
        }
        asm volatile("s_waitcnt lgkmcnt(0)" ::: "memory");
        bf16x8 pa[2];
        #pragma unroll
        for (int kc = 0; kc < 2; ++kc)
            pa[kc] = *(const bf16x8*)(pw + fr * 64 + (((kc * 4 + g) ^ (fr & 7)) << 3));

        __builtin_amdgcn_s_setprio(1);
        #pragma unroll
        for (int jd = 0; jd < 4; ++jd) {
            const int d = jd * 16 + fr;
            const int key = ((d >> 3) ^ d) & 7;
            #pragma unroll
            for (int kc = 0; kc < 2; ++kc) {
                bf16x8 vf = *(const bf16x8*)(Vt + d * 64 + (((kc * 4 + g) ^ key) << 3));
                acc[jd] = __builtin_amdgcn_mfma_f32_16x16x32_bf16(pa[kc], vf, acc[jd], 0, 0, 0);
            }
        }
        __builtin_amdgcn_s_setprio(0);

        if (kt < last) {
            __syncthreads();
            #pragma unroll
            for (int it = 0; it < 4; ++it) {
                const int row = it * 16 + r0;
                *(bf16x8*)(Ks + row * 64 + ((ch ^ (row & 7)) << 3)) = kr[it];
                #pragma unroll
                for (int j = 0; j < 8; ++j) {
                    const int d = ch * 8 + j;
                    const int key = ((d >> 3) ^ d) & 7;
                    Vt[d * 64 + ((((row >> 3) ^ key) << 3) + (row & 7))] = vr[it][j];
                }
            }
            __syncthreads();
        }
    }

    #pragma unroll
    for (int r = 0; r < 4; ++r) {
        const float inv = 1.0f / l[r];
        const int q = q0w + g * 4 + r;
        __bf16* yp = y + ((size_t)(b * TDIM + q)) * EDIM + h * 64;
        #pragma unroll
        for (int jd = 0; jd < 4; ++jd)
            yp[jd * 16 + fr] = (__bf16)(acc[jd][r] * inv);
    }
}

// ---------------------------------------------------------------- fused-LSE finalize
__global__ __launch_bounds__(256) void lsefin_kernel(
    const float* __restrict__ part, const float* __restrict__ logits,
    const int* __restrict__ targets, float* __restrict__ rr)
{
    const int row = blockIdx.x, tid = threadIdx.x;
    float s = 0.f;
    for (int j = tid; j < NPB; j += 256) s += part[(size_t)row * NPB + j];
    #pragma unroll
    for (int off = 32; off; off >>= 1) s += __shfl_xor(s, off);
    __shared__ float red[4];
    if ((tid & 63) == 0) red[tid >> 6] = s;
    __syncthreads();
    if (tid == 0) {
        float S = red[0] + red[1] + red[2] + red[3];
        rr[row] = logf(S) - logits[(size_t)row * VDIM + targets[row]];
    }
}

__global__ __launch_bounds__(256) void loss_reduce_kernel(
    const float* __restrict__ rr, float* __restrict__ out)
{
    const int tid = threadIdx.x;
    float s = 0.f;
    for (int i = tid; i < BT; i += 256) s += rr[i];
    #pragma unroll
    for (int off = 32; off; off >>= 1) s += __shfl_xor(s, off);
    __shared__ float red[4];
    if ((tid & 63) == 0) red[tid >> 6] = s;
    __syncthreads();
    if (tid == 0) out[0] = (red[0] + red[1] + red[2] + red[3]) * (1.0f / BT);
}

// ---------------------------------------------------------------- launch
extern "C" void kernel_launch(void* const* d_in, const int* in_sizes, int n_in,
                              void* d_out, int out_size, void* d_ws, size_t ws_size,
                              hipStream_t stream)
{
    const int*   idx     = (const int*)d_in[0];
    const int*   targets = (const int*)d_in[1];
    const float* wte     = (const float*)d_in[2];
    const float* wpe     = (const float*)d_in[3];
    const float* ln1_w   = (const float*)d_in[4];
    const float* ln1_b   = (const float*)d_in[5];
    const float* attn_w  = (const float*)d_in[6];
    const float* attn_b  = (const float*)d_in[7];
    const float* proj_w  = (const float*)d_in[8];
    const float* proj_b  = (const float*)d_in[9];
    const float* ln2_w   = (const float*)d_in[10];
    const float* ln2_b   = (const float*)d_in[11];
    const float* fc_w    = (const float*)d_in[12];
    const float* fc_b    = (const float*)d_in[13];
    const float* fcp_w   = (const float*)d_in[14];
    const float* fcp_b   = (const float*)d_in[15];
    const float* lnf_w   = (const float*)d_in[16];
    const float* lnf_b   = (const float*)d_in[17];

    float* logits = (float*)d_out;

    const size_t slq = (size_t)EDIM * E3, slp = (size_t)EDIM * EDIM;
    const size_t slf = (size_t)EDIM * E4, slfp = (size_t)E4 * EDIM;

    char* wp = (char*)d_ws;
    float*  x     = (float*)wp;   wp += (size_t)BT * EDIM * 4;
    __bf16* qkvb  = (__bf16*)wp;  wp += (size_t)BT * E3 * 2;
    __bf16* xnbf  = (__bf16*)wp;  wp += (size_t)BT * EDIM * 2;
    __bf16* ybf   = (__bf16*)wp;  wp += (size_t)BT * EDIM * 2;
    __bf16* hbf   = (__bf16*)wp;  wp += (size_t)BT * E4 * 2;
    __bf16* wteb  = (__bf16*)wp;  wp += (size_t)VDIM * EDIM * 2;
    float*  part  = (float*)wp;   wp += (size_t)BT * NPB * 4;
    float*  psum  = (float*)wp;   wp += (size_t)2 * BT * EDIM * 4;
    float*  rr    = (float*)wp;   wp += (size_t)BT * 4;
    __bf16* wqkvb = (__bf16*)wp;

    const size_t wbytes_all = (slq + slp + slf + slfp) * 2 * LNUM;
    const size_t used = (size_t)(wp - (char*)d_ws);
    const bool big = ws_size >= used + wbytes_all;
    const size_t L = big ? LNUM : 1;
    __bf16* wprjb = wqkvb + slq * L;
    __bf16* wfcb  = wprjb + slp * L;
    __bf16* wfpb  = wfcb  + slf * L;

    embed_kernel<<<BT, 256, 0, stream>>>(idx, wte, wpe, x);
    cvt_kernel<<<2048, 256, 0, stream>>>(wte, wteb, (long)VDIM * EDIM / 4);

    if (big) {
        convt_kernel<<<dim3(E3 / 32, EDIM / 32, LNUM), 256, 0, stream>>>(attn_w, wqkvb, EDIM, E3);
        convt_kernel<<<dim3(EDIM / 32, EDIM / 32, LNUM), 256, 0, stream>>>(proj_w, wprjb, EDIM, EDIM);
        convt_kernel<<<dim3(E4 / 32, EDIM / 32, LNUM), 256, 0, stream>>>(fc_w, wfcb, EDIM, E4);
        convt_kernel<<<dim3(EDIM / 32, E4 / 32, LNUM), 256, 0, stream>>>(fcp_w, wfpb, E4, EDIM);
    }

    ln_kernel<<<BT / 4, 256, 0, stream>>>(x, ln1_w, ln1_b, xnbf);

    for (int l = 0; l < LNUM; ++l) {
        const __bf16* wq = wqkvb + (big ? (size_t)l * slq : 0);
        const __bf16* wpj = wprjb + (big ? (size_t)l * slp : 0);
        const __bf16* wf = wfcb + (big ? (size_t)l * slf : 0);
        const __bf16* wfp = wfpb + (big ? (size_t)l * slfp : 0);

        if (!big)
            convt_kernel<<<dim3(E3 / 32, EDIM / 32), 256, 0, stream>>>(
                attn_w + (size_t)l * slq, (__bf16*)wq, EDIM, E3);
        mgemm<64, 64, 64, true, false, false, true, false>
            <<<dim3(E3 / 64, BT / 64), 256, 0, stream>>>(
            xnbf, wq, attn_b + (size_t)l * E3, nullptr, qkvb, BT, E3, EDIM, EDIM);
        fattn_kernel<<<dim3(TDIM / 32, HNUM, BDIM), 128, 0, stream>>>(qkvb, ybf);
        if (!big)
            convt_kernel<<<dim3(EDIM / 32, EDIM / 32), 256, 0, stream>>>(
                proj_w + (size_t)l * slp, (__bf16*)wpj, EDIM, EDIM);
        mgemm<64, 64, 64, false, false, false, false, false>
            <<<dim3(EDIM / 64, BT / 64, 2), 256, 0, stream>>>(
            ybf, wpj, nullptr, nullptr, psum, BT, EDIM, EDIM / 2, EDIM);
        redln_kernel<<<BT / 4, 256, 0, stream>>>(
            psum, proj_b + (size_t)l * EDIM, x,
            ln2_w + (size_t)l * EDIM, ln2_b + (size_t)l * EDIM, xnbf);
        if (!big)
            convt_kernel<<<dim3(E4 / 32, EDIM / 32), 256, 0, stream>>>(
                fc_w + (size_t)l * slf, (__bf16*)wf, EDIM, E4);
        mgemm<64, 64, 64, true, true, false, true, false>
            <<<dim3(E4 / 64, BT / 64), 256, 0, stream>>>(
            xnbf, wf, fc_b + (size_t)l * E4, nullptr, hbf, BT, E4, EDIM, EDIM);
        if (!big)
            convt_kernel<<<dim3(EDIM / 32, E4 / 32), 256, 0, stream>>>(
                fcp_w + (size_t)l * slfp, (__bf16*)wfp, E4, EDIM);
        mgemm<64, 64, 64, false, false, false, false, false>
            <<<dim3(EDIM / 64, BT / 64, 2), 256, 0, stream>>>(
            hbf, wfp, nullptr, nullptr, psum, BT, EDIM, E4 / 2, E4);
        const float* nw = (l + 1 < LNUM) ? ln1_w + (size_t)(l + 1) * EDIM : lnf_w;
        const float* nb = (l + 1 < LNUM) ? ln1_b + (size_t)(l + 1) * EDIM : lnf_b;
        redln_kernel<<<BT / 4, 256, 0, stream>>>(
            psum, fcp_b + (size_t)l * EDIM, x, nw, nb, xnbf);
    }

    lgemm<<<dim3(64 * 50), 512, 0, stream>>>(
        xnbf, wteb, logits, part, BT, VDIM, EDIM);
    lsefin_kernel<<<BT, 256, 0, stream>>>(part, logits, targets, rr);
    loss_reduce_kernel<<<1, 256, 0, stream>>>(rr, logits + (size_t)BT * VDIM);
}

// Round 19
// 1937.543 us; speedup vs baseline: 1.0769x; 1.0167x over previous
//
#include <hip/hip_runtime.h>
#include <hip/hip_bf16.h>
#include <math.h>

#define LNUM 12
#define HNUM 12
#define EDIM 768
#define VDIM 50257
#define BDIM 2
#define TDIM 1024
#define BT (BDIM*TDIM)
#define E3 (3*EDIM)
#define E4 (4*EDIM)
#define NPB (2*((VDIM+127)/128))   // 786 per-64-col partials per row

typedef __bf16 bf16x8 __attribute__((ext_vector_type(8)));
typedef __bf16 bf16x4 __attribute__((ext_vector_type(4)));
typedef float f32x4 __attribute__((ext_vector_type(4)));

// tanh-approx GELU, rewritten: 0.5x(1+tanh(u)) == x*sigmoid(2u); one v_exp_f32
__device__ __forceinline__ float gelu_f(float x) {
    float u2 = 1.5957691216057308f * (x + 0.044715f * x * x * x);   // 2*0.7978845608*( . )
    return x / (1.0f + __expf(-u2));
}

// async global->LDS, 16B per lane
__device__ __forceinline__ void gl16(const void* g, void* l) {
    __builtin_amdgcn_global_load_lds(
        (const __attribute__((address_space(1))) unsigned int*)g,
        (__attribute__((address_space(3))) unsigned int*)l,
        16, 0, 0);
}

// ---------------------------------------------------------------- embedding
__global__ __launch_bounds__(256) void embed_kernel(
    const int* __restrict__ idx, const float* __restrict__ wte,
    const float* __restrict__ wpe, float* __restrict__ x)
{
    const int row = blockIdx.x;
    const int t = row % TDIM;
    const int tok = idx[row];
    const float* we = wte + (size_t)tok * EDIM;
    const float* pe = wpe + (size_t)t * EDIM;
    float* xr = x + (size_t)row * EDIM;
    for (int e = threadIdx.x; e < EDIM; e += 256) xr[e] = we[e] + pe[e];
}

// ---------------------------------------------------------------- layernorm (bf16 out)
__global__ __launch_bounds__(256) void ln_kernel(
    const float* __restrict__ in, const float* __restrict__ w,
    const float* __restrict__ b, __bf16* __restrict__ out)
{
    const int row = blockIdx.x * 4 + (threadIdx.x >> 6);
    const int lane = threadIdx.x & 63;
    const float4* xr = (const float4*)(in + (size_t)row * EDIM);
    float4 a0 = xr[lane], a1 = xr[64 + lane], a2 = xr[128 + lane];
    float s = a0.x + a0.y + a0.z + a0.w + a1.x + a1.y + a1.z + a1.w
            + a2.x + a2.y + a2.z + a2.w;
    #pragma unroll
    for (int off = 32; off; off >>= 1) s += __shfl_xor(s, off);
    const float mean = s * (1.0f / EDIM);
    float4 d0 = make_float4(a0.x - mean, a0.y - mean, a0.z - mean, a0.w - mean);
    float4 d1 = make_float4(a1.x - mean, a1.y - mean, a1.z - mean, a1.w - mean);
    float4 d2 = make_float4(a2.x - mean, a2.y - mean, a2.z - mean, a2.w - mean);
    float v = d0.x*d0.x + d0.y*d0.y + d0.z*d0.z + d0.w*d0.w
            + d1.x*d1.x + d1.y*d1.y + d1.z*d1.z + d1.w*d1.w
            + d2.x*d2.x + d2.y*d2.y + d2.z*d2.z + d2.w*d2.w;
    #pragma unroll
    for (int off = 32; off; off >>= 1) v += __shfl_xor(v, off);
    const float inv = rsqrtf(v * (1.0f / EDIM) + 1e-5f);
    const float4* w4 = (const float4*)w;
    const float4* b4 = (const float4*)b;
    __bf16* orow = out + (size_t)row * EDIM;
    #pragma unroll
    for (int c = 0; c < 3; ++c) {
        float4 dd = c == 0 ? d0 : (c == 1 ? d1 : d2);
        float4 ww = w4[c * 64 + lane], bb = b4[c * 64 + lane];
        bf16x4 o;
        o[0] = (__bf16)(dd.x * inv * ww.x + bb.x);
        o[1] = (__bf16)(dd.y * inv * ww.y + bb.y);
        o[2] = (__bf16)(dd.z * inv * ww.z + bb.z);
        o[3] = (__bf16)(dd.w * inv * ww.w + bb.w);
        *(bf16x4*)(orow + c * 256 + lane * 4) = o;
    }
}

// ------------------------------------------- split-K reduce + bias + residual + LN
__global__ __launch_bounds__(256) void redln_kernel(
    const float* __restrict__ ps, const float* __restrict__ bias,
    float* __restrict__ x, const float* __restrict__ w,
    const float* __restrict__ b, __bf16* __restrict__ out)
{
    const int row = blockIdx.x * 4 + (threadIdx.x >> 6);
    const int lane = threadIdx.x & 63;
    const float4* p0 = (const float4*)(ps + (size_t)row * EDIM);
    const float4* p1 = (const float4*)(ps + (size_t)(BT + row) * EDIM);
    float4* xr = (float4*)(x + (size_t)row * EDIM);
    const float4* b4 = (const float4*)bias;
    float4 a[3];
    #pragma unroll
    for (int c = 0; c < 3; ++c) {
        const int i = c * 64 + lane;
        float4 u = p0[i], v = p1[i], xx = xr[i], bb = b4[i];
        a[c] = make_float4(u.x + v.x + xx.x + bb.x, u.y + v.y + xx.y + bb.y,
                           u.z + v.z + xx.z + bb.z, u.w + v.w + xx.w + bb.w);
        xr[i] = a[c];
    }
    float s = a[0].x + a[0].y + a[0].z + a[0].w + a[1].x + a[1].y + a[1].z + a[1].w
            + a[2].x + a[2].y + a[2].z + a[2].w;
    #pragma unroll
    for (int off = 32; off; off >>= 1) s += __shfl_xor(s, off);
    const float mean = s * (1.0f / EDIM);
    float v = 0.f;
    #pragma unroll
    for (int c = 0; c < 3; ++c) {
        a[c] = make_float4(a[c].x - mean, a[c].y - mean, a[c].z - mean, a[c].w - mean);
        v += a[c].x * a[c].x + a[c].y * a[c].y + a[c].z * a[c].z + a[c].w * a[c].w;
    }
    #pragma unroll
    for (int off = 32; off; off >>= 1) v += __shfl_xor(v, off);
    const float inv = rsqrtf(v * (1.0f / EDIM) + 1e-5f);
    const float4* w4 = (const float4*)w;
    const float4* lb4 = (const float4*)b;
    __bf16* orow = out + (size_t)row * EDIM;
    #pragma unroll
    for (int c = 0; c < 3; ++c) {
        float4 ww = w4[c * 64 + lane], bb = lb4[c * 64 + lane];
        bf16x4 o;
        o[0] = (__bf16)(a[c].x * inv * ww.x + bb.x);
        o[1] = (__bf16)(a[c].y * inv * ww.y + bb.y);
        o[2] = (__bf16)(a[c].z * inv * ww.z + bb.z);
        o[3] = (__bf16)(a[c].w * inv * ww.w + bb.w);
        *(bf16x4*)(orow + c * 256 + lane * 4) = o;
    }
}

// ------------------------------------------------- weight convert: f32 [K][N] -> bf16 [N][K]
__global__ __launch_bounds__(256) void convt_kernel(
    const float* __restrict__ in, __bf16* __restrict__ out, int K, int N)
{
    in  += (size_t)blockIdx.z * K * N;
    out += (size_t)blockIdx.z * K * N;
    __shared__ float t[32][33];
    const int n0 = blockIdx.x * 32, k0 = blockIdx.y * 32;
    const int r = threadIdx.x >> 3, c = (threadIdx.x & 7) * 4;
    float4 v = *(const float4*)(in + (size_t)(k0 + r) * N + n0 + c);
    t[r][c + 0] = v.x; t[r][c + 1] = v.y; t[r][c + 2] = v.z; t[r][c + 3] = v.w;
    __syncthreads();
    bf16x4 o;
    o[0] = (__bf16)t[c + 0][r];
    o[1] = (__bf16)t[c + 1][r];
    o[2] = (__bf16)t[c + 2][r];
    o[3] = (__bf16)t[c + 3][r];
    *(bf16x4*)(out + (size_t)(n0 + r) * K + k0 + c) = o;
}

// ------------------------------------------------- elementwise f32 -> bf16 (wte)
__global__ __launch_bounds__(256) void cvt_kernel(
    const float* __restrict__ in, __bf16* __restrict__ out, long n4)
{
    for (long i = blockIdx.x * 256L + threadIdx.x; i < n4; i += (long)gridDim.x * 256L) {
        float4 v = ((const float4*)in)[i];
        out[i * 4 + 0] = (__bf16)v.x;
        out[i * 4 + 1] = (__bf16)v.y;
        out[i * 4 + 2] = (__bf16)v.z;
        out[i * 4 + 3] = (__bf16)v.w;
    }
}

// ---------------------------------------------------------------- MFMA GEMM (layer GEMMs)
// 48 KB LDS -> 3 blocks/CU; hint the occupancy so the allocator targets it.
template<int BM, int BN, int BK, bool BIAS, bool GELU_, bool RES_, bool OUTBF, bool NGUARD>
__global__ __launch_bounds__(256, 3) void mgemm(
    const __bf16* __restrict__ A, const __bf16* __restrict__ Bt,
    const float* __restrict__ bias, const float* __restrict__ res,
    void* __restrict__ Cout, int M, int N, int K, int lda)
{
    constexpr int WM = BM / 2, WN = BN / 2;
    constexpr int FM = WM / 16, FN = WN / 16;
    constexpr int KS = BK / 32;
    constexpr int TBA = BM * BK * 2;
    constexpr int TBB = BN * BK * 2;
    constexpr int rA = TBA / 4096, rB = TBB / 4096;
    constexpr int RPI = 2048 / BK;
    constexpr int CPR = BK / 8;
    __shared__ __align__(16) __bf16 As[3 * BM * BK];
    __shared__ __align__(16) __bf16 Bs[3 * BN * BK];
    const int tid = threadIdx.x;
    const int lane = tid & 63;
    const int wave = tid >> 6;
    const int wr = wave >> 1, wc = wave & 1;

    const int bm = blockIdx.y, bn = blockIdx.x;
    const int m0 = bm * BM;
    const int n0 = bn * BN;
    const int kbase = blockIdx.z * K;
    const size_t zoff = (size_t)blockIdx.z * M * N;

    const int srow = tid / CPR;
    const int skey = (BK == 32) ? ((srow >> 1) & 3) : (srow & 7);
    const int c0 = (tid % CPR) ^ skey;

    const __bf16* gA = A + (size_t)(m0 + srow) * lda + kbase + c0 * 8;
    const __bf16* gB[rB];
    #pragma unroll
    for (int r = 0; r < rB; ++r) {
        int nr = n0 + srow + r * RPI;
        if (NGUARD) nr = nr < N ? nr : N - 1;
        gB[r] = Bt + (size_t)nr * lda + kbase + c0 * 8;
    }

    const int fr = lane & 15;
    const int g = lane >> 4;
    const int fkey = (BK == 32) ? ((fr >> 1) & 3) : (fr & 7);

    f32x4 acc[FM][FN];
    #pragma unroll
    for (int i = 0; i < FM; i++)
        #pragma unroll
        for (int j = 0; j < FN; j++) acc[i][j] = (f32x4){0.f, 0.f, 0.f, 0.f};

    const int nt = K / BK;

    auto stage = [&](int kk, int b) {
        #pragma unroll
        for (int r = 0; r < rA; ++r)
            gl16(gA + (size_t)r * RPI * lda + kk, (char*)As + b * TBA + r * 4096 + tid * 16);
        #pragma unroll
        for (int r = 0; r < rB; ++r)
            gl16(gB[r] + kk, (char*)Bs + b * TBB + r * 4096 + tid * 16);
    };

    stage(0, 0);
    if (nt > 1) stage(BK, 1);

    int b0 = 0, b1 = 1, b2 = 2;
    for (int t = 0; t < nt; ++t) {
        if (t + 1 < nt) {
            static_assert(rA + rB == 4 || rA + rB == 6, "vmcnt literal");
            if constexpr (rA + rB == 4) asm volatile("s_waitcnt vmcnt(4)" ::: "memory");
            else                        asm volatile("s_waitcnt vmcnt(6)" ::: "memory");
        } else {
            asm volatile("s_waitcnt vmcnt(0)" ::: "memory");
        }
        asm volatile("s_barrier" ::: "memory");
        if (t + 2 < nt) stage((t + 2) * BK, b2);

        const char* pa = (const char*)As + b0 * TBA;
        const char* pb = (const char*)Bs + b0 * TBB;
        bf16x8 af[FM][KS], bfr[FN][KS];
        #pragma unroll
        for (int i = 0; i < FM; i++)
            #pragma unroll
            for (int kc = 0; kc < KS; kc++)
                af[i][kc] = *(const bf16x8*)(pa + (wr * WM + i * 16 + fr) * (2 * BK)
                                                + (((kc * 4 + g) ^ fkey) << 4));
        #pragma unroll
        for (int j = 0; j < FN; j++)
            #pragma unroll
            for (int kc = 0; kc < KS; kc++)
                bfr[j][kc] = *(const bf16x8*)(pb + (wc * WN + j * 16 + fr) * (2 * BK)
                                                 + (((kc * 4 + g) ^ fkey) << 4));
        #pragma unroll
        for (int kc = 0; kc < KS; kc++)
            #pragma unroll
            for (int i = 0; i < FM; i++)
                #pragma unroll
                for (int j = 0; j < FN; j++)
                    acc[i][j] = __builtin_amdgcn_mfma_f32_16x16x32_bf16(af[i][kc], bfr[j][kc], acc[i][j], 0, 0, 0);
        const int tmp = b0; b0 = b1; b1 = b2; b2 = tmp;
    }

    const int crow = g * 4;
    #pragma unroll
    for (int i = 0; i < FM; i++) {
        #pragma unroll
        for (int r = 0; r < 4; r++) {
            const int m = m0 + wr * WM + i * 16 + crow + r;
            #pragma unroll
            for (int j = 0; j < FN; j++) {
                const int n = n0 + wc * WN + j * 16 + fr;
                if (!NGUARD || n < N) {
                    float v = acc[i][j][r];
                    if (BIAS) v += bias[n];
                    if (GELU_) v = gelu_f(v);
                    if (RES_) v += res[(size_t)m * N + n];
                    if (OUTBF) ((__bf16*)Cout)[zoff + (size_t)m * N + n] = (__bf16)v;
                    else       ((float*)Cout)[zoff + (size_t)m * N + n] = v;
                }
            }
        }
    }
}

// ---------------------------------------------------------------- logits GEMM (phase-interleaved)
// R15 config (best measured): 512 threads (8 waves, 4M x 2N), BM=256 BN=128
// BK=64, 3 LDS buffers, ONE barrier per K-tile, counted vmcnt(6), 2 phases/tile.
__global__ __launch_bounds__(512, 1) void lgemm(
    const __bf16* __restrict__ A, const __bf16* __restrict__ Bt,
    float* __restrict__ Cout, float* __restrict__ part, int M, int N, int K)
{
    __shared__ __align__(16) __bf16 As[3 * 256 * 64];   // 96 KB
    __shared__ __align__(16) __bf16 Bs[3 * 128 * 64];   // 48 KB
    const int tid = threadIdx.x;
    const int lane = tid & 63;
    const int wave = tid >> 6;
    const int wm = wave >> 1, wn = wave & 1;

    const int wg = blockIdx.x;
    const int bm = (wg >> 3) & 7;
    const int bn = (wg & 7) + ((wg >> 6) << 3);
    if (bn * 128 >= N) return;
    const int m0 = bm * 256, n0 = bn * 128;

    const int srow = tid >> 3;
    const int c0 = (tid & 7) ^ (srow & 7);
    const __bf16* gA = A + (size_t)(m0 + srow) * K + c0 * 8;
    const __bf16* gB[2];
    #pragma unroll
    for (int r = 0; r < 2; ++r) {
        int nr = n0 + r * 64 + srow;
        nr = nr < N ? nr : N - 1;
        gB[r] = Bt + (size_t)nr * K + c0 * 8;
    }

    const int fr = lane & 15;
    const int g = lane >> 4;
    const int fk = fr & 7;

    auto stageA = [&](int kk, int b, int r) {
        gl16(gA + (size_t)r * 64 * K + kk, (char*)As + b * 32768 + r * 8192 + tid * 16);
    };
    auto stageB = [&](int kk, int b, int r) {
        gl16(gB[r] + kk, (char*)Bs + b * 16384 + r * 8192 + tid * 16);
    };

    f32x4 acc[4][4];
    #pragma unroll
    for (int i = 0; i < 4; i++)
        #pragma unroll
        for (int j = 0; j < 4; j++) acc[i][j] = (f32x4){0.f, 0.f, 0.f, 0.f};

    const int nt = K >> 6;   // 12
    #pragma unroll
    for (int r = 0; r < 4; ++r) stageA(0, 0, r);
    #pragma unroll
    for (int r = 0; r < 2; ++r) stageB(0, 0, r);
    #pragma unroll
    for (int r = 0; r < 4; ++r) stageA(64, 1, r);
    #pragma unroll
    for (int r = 0; r < 2; ++r) stageB(64, 1, r);

    for (int t = 0; t < nt; ++t) {
        const int bt = t % 3;
        if (t + 1 < nt) asm volatile("s_waitcnt vmcnt(6)" ::: "memory");
        else            asm volatile("s_waitcnt vmcnt(0)" ::: "memory");
        asm volatile("s_barrier" ::: "memory");

        const char* pa = (const char*)As + bt * 32768;
        const char* pb = (const char*)Bs + bt * 16384;
        const int kk2 = (t + 2) * 64;
        const int b2 = (t + 2) % 3;

        bf16x8 bfr[4][2], af[2][2];
        #pragma unroll
        for (int j = 0; j < 4; ++j)
            #pragma unroll
            for (int kc = 0; kc < 2; ++kc)
                bfr[j][kc] = *(const bf16x8*)(pb + (wn * 64 + j * 16 + fr) * 128
                                                 + (((kc * 4 + g) ^ fk) << 4));
        #pragma unroll
        for (int i = 0; i < 2; ++i)
            #pragma unroll
            for (int kc = 0; kc < 2; ++kc)
                af[i][kc] = *(const bf16x8*)(pa + (wm * 64 + i * 16 + fr) * 128
                                                + (((kc * 4 + g) ^ fk) << 4));
        if (t + 2 < nt) { stageA(kk2, b2, 0); stageA(kk2, b2, 1); stageA(kk2, b2, 2); }
        __builtin_amdgcn_s_setprio(1);
        #pragma unroll
        for (int kc = 0; kc < 2; ++kc)
            #pragma unroll
            for (int i = 0; i < 2; ++i)
                #pragma unroll
                for (int j = 0; j < 4; ++j)
                    acc[i][j] = __builtin_amdgcn_mfma_f32_16x16x32_bf16(af[i][kc], bfr[j][kc], acc[i][j], 0, 0, 0);
        __builtin_amdgcn_s_setprio(0);

        bf16x8 af1[2][2];
        #pragma unroll
        for (int i = 0; i < 2; ++i)
            #pragma unroll
            for (int kc = 0; kc < 2; ++kc)
                af1[i][kc] = *(const bf16x8*)(pa + (wm * 64 + (i + 2) * 16 + fr) * 128
                                                 + (((kc * 4 + g) ^ fk) << 4));
        if (t + 2 < nt) { stageA(kk2, b2, 3); stageB(kk2, b2, 0); stageB(kk2, b2, 1); }
        __builtin_amdgcn_s_setprio(1);
        #pragma unroll
        for (int kc = 0; kc < 2; ++kc)
            #pragma unroll
            for (int i = 0; i < 2; ++i)
                #pragma unroll
                for (int j = 0; j < 4; ++j)
                    acc[i + 2][j] = __builtin_amdgcn_mfma_f32_16x16x32_bf16(af1[i][kc], bfr[j][kc], acc[i + 2][j], 0, 0, 0);
        __builtin_amdgcn_s_setprio(0);
    }

    // epilogue: f32 stores + per-64-col sum-exp partials
    const int crow = g * 4;
    const int cg = bn * 2 + wn;
    #pragma unroll
    for (int i = 0; i < 4; i++) {
        #pragma unroll
        for (int r = 0; r < 4; r++) {
            const int m = m0 + wm * 64 + i * 16 + crow + r;
            float se = 0.f;
            #pragma unroll
            for (int j = 0; j < 4; j++) {
                const int n = n0 + wn * 64 + j * 16 + fr;
                if (n < N) {
                    float v = acc[i][j][r];
                    Cout[(size_t)m * N + n] = v;
                    se += __expf(v);
                }
            }
            se += __shfl_xor(se, 1); se += __shfl_xor(se, 2);
            se += __shfl_xor(se, 4); se += __shfl_xor(se, 8);
            if (fr == 0 && (n0 + wn * 64) < N)
                part[(size_t)m * NPB + cg] = se;
        }
    }
}

// ---------------------------------------------------------------- flash attention (bf16 MFMA)
__global__ __launch_bounds__(128) void fattn_kernel(
    const __bf16* __restrict__ qkv, __bf16* __restrict__ y)
{
    const int bq = gridDim.x - 1 - blockIdx.x;
    const int h = blockIdx.y, b = blockIdx.z;
    const int tid = threadIdx.x, lane = tid & 63, w = tid >> 6;
    const int fr = lane & 15, g = lane >> 4;

    __shared__ __align__(16) __bf16 Ks[64 * 64];
    __shared__ __align__(16) __bf16 Vt[64 * 64];
    __shared__ __align__(16) __bf16 Ps[2][16 * 64];

    const __bf16* base = qkv + (size_t)b * TDIM * E3;
    const int q0w = bq * 32 + w * 16;
    const int NT = (bq >> 1) + 1;
    const int last = NT - 1;

    bf16x8 qf[2];
    {
        const __bf16* qp = base + (size_t)(q0w + fr) * E3 + h * 64 + g * 8;
        qf[0] = *(const bf16x8*)qp;
        qf[1] = *(const bf16x8*)(qp + 32);
        const __bf16 sc = (__bf16)0.125f;   // exact (power of two)
        #pragma unroll
        for (int e = 0; e < 8; ++e) { qf[0][e] *= sc; qf[1][e] *= sc; }
    }

    const int r0 = tid >> 3, ch = tid & 7;
    bf16x8 kr[4], vr[4];

    #pragma unroll
    for (int it = 0; it < 4; ++it) {
        const int row = it * 16 + r0;
        const __bf16* gp = base + (size_t)row * E3 + EDIM + h * 64 + ch * 8;
        kr[it] = *(const bf16x8*)gp;
        vr[it] = *(const bf16x8*)(gp + EDIM);
    }
    #pragma unroll
    for (int it = 0; it < 4; ++it) {
        const int row = it * 16 + r0;
        *(bf16x8*)(Ks + row * 64 + ((ch ^ (row & 7)) << 3)) = kr[it];
        #pragma unroll
        for (int j = 0; j < 8; ++j) {
            const int d = ch * 8 + j;
            const int key = ((d >> 3) ^ d) & 7;
            Vt[d * 64 + ((((row >> 3) ^ key) << 3) + (row & 7))] = vr[it][j];
        }
    }
    __syncthreads();

    float m[4] = {-1e30f, -1e30f, -1e30f, -1e30f};
    float l[4] = {0.f, 0.f, 0.f, 0.f};
    f32x4 acc[4];
    #pragma unroll
    for (int jd = 0; jd < 4; ++jd) acc[jd] = (f32x4){0.f, 0.f, 0.f, 0.f};

    for (int kt = 0; kt < NT; ++kt) {
        if (kt < last) {
            const int k1 = (kt + 1) * 64;
            #pragma unroll
            for (int it = 0; it < 4; ++it) {
                const int row = it * 16 + r0;
                const __bf16* gp = base + (size_t)(k1 + row) * E3 + EDIM + h * 64 + ch * 8;
                kr[it] = *(const bf16x8*)gp;
                vr[it] = *(const bf16x8*)(gp + EDIM);
            }
        }

        const int k0 = kt * 64;
        f32x4 s[4];
        __builtin_amdgcn_s_setprio(1);
        #pragma unroll
        for (int jf = 0; jf < 4; ++jf) {
            const int krow = jf * 16 + fr;
            f32x4 sv = (f32x4){0.f, 0.f, 0.f, 0.f};
            #pragma unroll
            for (int kc = 0; kc < 2; ++kc) {
                bf16x8 kf = *(const bf16x8*)(Ks + krow * 64 + (((kc * 4 + g) ^ (fr & 7)) << 3));
                sv = __builtin_amdgcn_mfma_f32_16x16x32_bf16(qf[kc], kf, sv, 0, 0, 0);
            }
            s[jf] = sv;
        }
        __builtin_amdgcn_s_setprio(0);
        if (kt == last) {
            #pragma unroll
            for (int jf = 0; jf < 4; ++jf) {
                const int k = k0 + jf * 16 + fr;
                #pragma unroll
                for (int r = 0; r < 4; ++r) {
                    const int q = q0w + g * 4 + r;
                    if (k > q) s[jf][r] = -1e30f;
                }
            }
        }

        #pragma unroll
        for (int r = 0; r < 4; ++r) {
            float mx = fmaxf(fmaxf(s[0][r], s[1][r]), fmaxf(s[2][r], s[3][r]));
            mx = fmaxf(mx, __shfl_xor(mx, 1));
            mx = fmaxf(mx, __shfl_xor(mx, 2));
            mx = fmaxf(mx, __shfl_xor(mx, 4));
            mx = fmaxf(mx, __shfl_xor(mx, 8));
            const float mn = fmaxf(m[r], mx);
            const float sc2 = __expf(m[r] - mn);
            m[r] = mn;
            float rs = 0.f;
            #pragma unroll
            for (int jf = 0; jf < 4; ++jf) {
                const float p = __expf(s[jf][r] - mn);
                s[jf][r] = p;
                rs += p;
            }
            rs += __shfl_xor(rs, 1);
            rs += __shfl_xor(rs, 2);
            rs += __shfl_xor(rs, 4);
            rs += __shfl_xor(rs, 8);
            l[r] = l[r] * sc2 + rs;
            #pragma unroll
            for (int jd = 0; jd < 4; ++jd) acc[jd][r] *= sc2;
        }

        __bf16* pw = &Ps[w][0];
        #pragma unroll
        for (int jf = 0; jf < 4; ++jf) {
            const int chp = jf * 2 + (fr >> 3);
            #pragma unroll
            for (int r = 0; r < 4; ++r) {
                const int row = g * 4 + r;
                pw[row * 64 + (((chp ^ (row & 7)) << 3) + (fr & 7))] = (__bf16)s[jf][r];
            }
        }
        asm volatile("s_waitcnt lgkmcnt(0)" ::: "memory");
        bf16x8 pa[2];
        #pragma unroll
        for (int kc = 0; kc < 2; ++kc)
            pa[kc] = *(const bf16x8*)(pw + fr * 64 + (((kc * 4 + g) ^ (fr & 7)) << 3));

        __builtin_amdgcn_s_setprio(1);
        #pragma unroll
        for (int jd = 0; jd < 4; ++jd) {
            const int d = jd * 16 + fr;
            const int key = ((d >> 3) ^ d) & 7;
            #pragma unroll
            for (int kc = 0; kc < 2; ++kc) {
                bf16x8 vf = *(const bf16x8*)(Vt + d * 64 + (((kc * 4 + g) ^ key) << 3));
                acc[jd] = __builtin_amdgcn_mfma_f32_16x16x32_bf16(pa[kc], vf, acc[jd], 0, 0, 0);
            }
        }
        __builtin_amdgcn_s_setprio(0);

        if (kt < last) {
            __syncthreads();
            #pragma unroll
            for (int it = 0; it < 4; ++it) {
                const int row = it * 16 + r0;
                *(bf16x8*)(Ks + row * 64 + ((ch ^ (row & 7)) << 3)) = kr[it];
                #pragma unroll
                for (int j = 0; j < 8; ++j) {
                    const int d = ch * 8 + j;
                    const int key = ((d >> 3) ^ d) & 7;
                    Vt[d * 64 + ((((row >> 3) ^ key) << 3) + (row & 7))] = vr[it][j];
                }
            }
            __syncthreads();
        }
    }

    #pragma unroll
    for (int r = 0; r < 4; ++r) {
        const float inv = 1.0f / l[r];
        const int q = q0w + g * 4 + r;
        __bf16* yp = y + ((size_t)(b * TDIM + q)) * EDIM + h * 64;
        #pragma unroll
        for (int jd = 0; jd < 4; ++jd)
            yp[jd * 16 + fr] = (__bf16)(acc[jd][r] * inv);
    }
}

// ---------------------------------------------------------------- fused-LSE finalize
__global__ __launch_bounds__(256) void lsefin_kernel(
    const float* __restrict__ part, const float* __restrict__ logits,
    const int* __restrict__ targets, float* __restrict__ rr)
{
    const int row = blockIdx.x, tid = threadIdx.x;
    float s = 0.f;
    for (int j = tid; j < NPB; j += 256) s += part[(size_t)row * NPB + j];
    #pragma unroll
    for (int off = 32; off; off >>= 1) s += __shfl_xor(s, off);
    __shared__ float red[4];
    if ((tid & 63) == 0) red[tid >> 6] = s;
    __syncthreads();
    if (tid == 0) {
        float S = red[0] + red[1] + red[2] + red[3];
        rr[row] = logf(S) - logits[(size_t)row * VDIM + targets[row]];
    }
}

__global__ __launch_bounds__(256) void loss_reduce_kernel(
    const float* __restrict__ rr, float* __restrict__ out)
{
    const int tid = threadIdx.x;
    float s = 0.f;
    for (int i = tid; i < BT; i += 256) s += rr[i];
    #pragma unroll
    for (int off = 32; off; off >>= 1) s += __shfl_xor(s, off);
    __shared__ float red[4];
    if ((tid & 63) == 0) red[tid >> 6] = s;
    __syncthreads();
    if (tid == 0) out[0] = (red[0] + red[1] + red[2] + red[3]) * (1.0f / BT);
}

// ---------------------------------------------------------------- launch
extern "C" void kernel_launch(void* const* d_in, const int* in_sizes, int n_in,
                              void* d_out, int out_size, void* d_ws, size_t ws_size,
                              hipStream_t stream)
{
    const int*   idx     = (const int*)d_in[0];
    const int*   targets = (const int*)d_in[1];
    const float* wte     = (const float*)d_in[2];
    const float* wpe     = (const float*)d_in[3];
    const float* ln1_w   = (const float*)d_in[4];
    const float* ln1_b   = (const float*)d_in[5];
    const float* attn_w  = (const float*)d_in[6];
    const float* attn_b  = (const float*)d_in[7];
    const float* proj_w  = (const float*)d_in[8];
    const float* proj_b  = (const float*)d_in[9];
    const float* ln2_w   = (const float*)d_in[10];
    const float* ln2_b   = (const float*)d_in[11];
    const float* fc_w    = (const float*)d_in[12];
    const float* fc_b    = (const float*)d_in[13];
    const float* fcp_w   = (const float*)d_in[14];
    const float* fcp_b   = (const float*)d_in[15];
    const float* lnf_w   = (const float*)d_in[16];
    const float* lnf_b   = (const float*)d_in[17];

    float* logits = (float*)d_out;

    const size_t slq = (size_t)EDIM * E3, slp = (size_t)EDIM * EDIM;
    const size_t slf = (size_t)EDIM * E4, slfp = (size_t)E4 * EDIM;

    char* wp = (char*)d_ws;
    float*  x     = (float*)wp;   wp += (size_t)BT * EDIM * 4;
    __bf16* qkvb  = (__bf16*)wp;  wp += (size_t)BT * E3 * 2;
    __bf16* xnbf  = (__bf16*)wp;  wp += (size_t)BT * EDIM * 2;
    __bf16* ybf   = (__bf16*)wp;  wp += (size_t)BT * EDIM * 2;
    __bf16* hbf   = (__bf16*)wp;  wp += (size_t)BT * E4 * 2;
    __bf16* wteb  = (__bf16*)wp;  wp += (size_t)VDIM * EDIM * 2;
    float*  part  = (float*)wp;   wp += (size_t)BT * NPB * 4;
    float*  psum  = (float*)wp;   wp += (size_t)2 * BT * EDIM * 4;
    float*  rr    = (float*)wp;   wp += (size_t)BT * 4;
    __bf16* wqkvb = (__bf16*)wp;

    const size_t wbytes_all = (slq + slp + slf + slfp) * 2 * LNUM;
    const size_t used = (size_t)(wp - (char*)d_ws);
    const bool big = ws_size >= used + wbytes_all;
    const size_t L = big ? LNUM : 1;
    __bf16* wprjb = wqkvb + slq * L;
    __bf16* wfcb  = wprjb + slp * L;
    __bf16* wfpb  = wfcb  + slf * L;

    embed_kernel<<<BT, 256, 0, stream>>>(idx, wte, wpe, x);
    cvt_kernel<<<2048, 256, 0, stream>>>(wte, wteb, (long)VDIM * EDIM / 4);

    if (big) {
        convt_kernel<<<dim3(E3 / 32, EDIM / 32, LNUM), 256, 0, stream>>>(attn_w, wqkvb, EDIM, E3);
        convt_kernel<<<dim3(EDIM / 32, EDIM / 32, LNUM), 256, 0, stream>>>(proj_w, wprjb, EDIM, EDIM);
        convt_kernel<<<dim3(E4 / 32, EDIM / 32, LNUM), 256, 0, stream>>>(fc_w, wfcb, EDIM, E4);
        convt_kernel<<<dim3(EDIM / 32, E4 / 32, LNUM), 256, 0, stream>>>(fcp_w, wfpb, E4, EDIM);
    }

    ln_kernel<<<BT / 4, 256, 0, stream>>>(x, ln1_w, ln1_b, xnbf);

    for (int l = 0; l < LNUM; ++l) {
        const __bf16* wq = wqkvb + (big ? (size_t)l * slq : 0);
        const __bf16* wpj = wprjb + (big ? (size_t)l * slp : 0);
        const __bf16* wf = wfcb + (big ? (size_t)l * slf : 0);
        const __bf16* wfp = wfpb + (big ? (size_t)l * slfp : 0);

        if (!big)
            convt_kernel<<<dim3(E3 / 32, EDIM / 32), 256, 0, stream>>>(
                attn_w + (size_t)l * slq, (__bf16*)wq, EDIM, E3);
        mgemm<64, 64, 64, true, false, false, true, false>
            <<<dim3(E3 / 64, BT / 64), 256, 0, stream>>>(
            xnbf, wq, attn_b + (size_t)l * E3, nullptr, qkvb, BT, E3, EDIM, EDIM);
        fattn_kernel<<<dim3(TDIM / 32, HNUM, BDIM), 128, 0, stream>>>(qkvb, ybf);
        if (!big)
            convt_kernel<<<dim3(EDIM / 32, EDIM / 32), 256, 0, stream>>>(
                proj_w + (size_t)l * slp, (__bf16*)wpj, EDIM, EDIM);
        mgemm<64, 64, 64, false, false, false, false, false>
            <<<dim3(EDIM / 64, BT / 64, 2), 256, 0, stream>>>(
            ybf, wpj, nullptr, nullptr, psum, BT, EDIM, EDIM / 2, EDIM);
        redln_kernel<<<BT / 4, 256, 0, stream>>>(
            psum, proj_b + (size_t)l * EDIM, x,
            ln2_w + (size_t)l * EDIM, ln2_b + (size_t)l * EDIM, xnbf);
        if (!big)
            convt_kernel<<<dim3(E4 / 32, EDIM / 32), 256, 0, stream>>>(
                fc_w + (size_t)l * slf, (__bf16*)wf, EDIM, E4);
        mgemm<64, 64, 64, true, true, false, true, false>
            <<<dim3(E4 / 64, BT / 64), 256, 0, stream>>>(
            xnbf, wf, fc_b + (size_t)l * E4, nullptr, hbf, BT, E4, EDIM, EDIM);
        if (!big)
            convt_kernel<<<dim3(EDIM / 32, E4 / 32), 256, 0, stream>>>(
                fcp_w + (size_t)l * slfp, (__bf16*)wfp, E4, EDIM);
        mgemm<64, 64, 64, false, false, false, false, false>
            <<<dim3(EDIM / 64, BT / 64, 2), 256, 0, stream>>>(
            hbf, wfp, nullptr, nullptr, psum, BT, EDIM, E4 / 2, E4);
        const float* nw = (l + 1 < LNUM) ? ln1_w + (size_t)(l + 1) * EDIM : lnf_w;
        const float* nb = (l + 1 < LNUM) ? ln1_b + (size_t)(l + 1) * EDIM : lnf_b;
        redln_kernel<<<BT / 4, 256, 0, stream>>>(
            psum, fcp_b + (size_t)l * EDIM, x, nw, nb, xnbf);
    }

    lgemm<<<dim3(64 * 50), 512, 0, stream>>>(
        xnbf, wteb, logits, part, BT, VDIM, EDIM);
    lsefin_kernel<<<BT, 256, 0, stream>>>(part, logits, targets, rr);
    loss_reduce_kernel<<<1, 256, 0, stream>>>(rr, logits + (size_t)BT * VDIM);
}